// Round 2
// baseline (2267.735 us; speedup 1.0000x reference)
//
#include <hip/hip_runtime.h>
#include <stdint.h>

typedef __attribute__((ext_vector_type(8))) short    bh8;   // 8 x bf16 (4 VGPR)
typedef __attribute__((ext_vector_type(4))) float    fx4;   // MFMA acc
typedef __attribute__((ext_vector_type(4))) float    f4v;
typedef unsigned short u16;
typedef __attribute__((ext_vector_type(4))) unsigned short u16x4;

#define DEV static __device__ __forceinline__

DEV u16 f2bf(float f) {                       // RNE fp32 -> bf16
  unsigned u = __float_as_uint(f);
  u += 0x7FFFu + ((u >> 16) & 1u);
  return (u16)(u >> 16);
}
DEV float bf2f(u16 s) { return __uint_as_float(((unsigned)s) << 16); }
DEV float softplus_f(float x) { return fmaxf(x, 0.f) + log1pf(expf(-fabsf(x))); }

DEV void gload_lds16(const u16* g, u16* l) {  // 16B/lane async global->LDS
  __builtin_amdgcn_global_load_lds(
      (const __attribute__((address_space(1))) unsigned int*)g,
      (__attribute__((address_space(3))) unsigned int*)l, 16, 0, 0);
}
DEV void stage2(const u16* s, u16* d) {       // one 128x64 half-tile (ld=2048)
  gload_lds16(s, d);
  gload_lds16(s + 131072, d + 4096);          // +64 rows
}

// ---------------- fp32 -> bf16 convert (vectorized) ----------------
__global__ __launch_bounds__(256) void k_cvt(const float* __restrict__ in,
                                             u16* __restrict__ out, int n4) {
  int i = blockIdx.x * 256 + threadIdx.x;
  int stride = gridDim.x * 256;
  for (; i < n4; i += stride) {
    f4v v = ((const f4v*)in)[i];
    u16x4 o;
    o.x = f2bf(v.x); o.y = f2bf(v.y); o.z = f2bf(v.z); o.w = f2bf(v.w);
    ((u16x4*)out)[i] = o;
  }
}

// ================= 256x256 8-phase GEMM (T2+T3+T4+T5) =================
// C[i,j] = sum_k A[i,k]*B[j,k]; M=16384, N=2048, K=2048 hardcoded.
// LDS (u16 idx): buf0.A [0,16384) buf0.B [16384,32768)
//                buf1.A [32768,49152) buf1.B [49152,65536)
// A/B tile: 256 rows x 64 cols, row-major, XOR-swizzle idx ^= (row&7)<<3 on
// ds_read; staging writes LINEAR dest with inverse-swizzled global source.
template <bool VM>
DEV void phase(const u16* __restrict__ lsg, int abase, int bbase,
               fx4 (&accq)[4][2], int arow0, int brow0, int ko8,
               const u16* ssrc, u16* sdst) {
  bh8 af[4][2], bv[2][2];
#pragma unroll
  for (int mi = 0; mi < 4; mi++) {
    int rr = arow0 + mi * 16;
    int sw = (rr & 7) << 3;
#pragma unroll
    for (int ks = 0; ks < 2; ks++)
      af[mi][ks] = *(const bh8*)&lsg[abase + rr * 64 + ((ks * 32 + ko8) ^ sw)];
  }
#pragma unroll
  for (int ni = 0; ni < 2; ni++) {
    int rr = brow0 + ni * 16;
    int sw = (rr & 7) << 3;
#pragma unroll
    for (int ks = 0; ks < 2; ks++)
      bv[ni][ks] = *(const bh8*)&lsg[bbase + rr * 64 + ((ks * 32 + ko8) ^ sw)];
  }
  stage2(ssrc, sdst);                  // prefetch one half-tile
  __builtin_amdgcn_s_barrier();
  __builtin_amdgcn_s_setprio(1);
#pragma unroll
  for (int ks = 0; ks < 2; ks++)
#pragma unroll
    for (int mi = 0; mi < 4; mi++)
#pragma unroll
      for (int ni = 0; ni < 2; ni++)
        accq[mi][ni] = __builtin_amdgcn_mfma_f32_16x16x32_bf16(
            af[mi][ks], bv[ni][ks], accq[mi][ni], 0, 0, 0);
  __builtin_amdgcn_s_setprio(0);
  if (VM) asm volatile("s_waitcnt vmcnt(4)" ::: "memory");  // counted, never 0
  asm volatile("s_waitcnt lgkmcnt(0)" ::: "memory");  // reads retired; pins stage hoist
  __builtin_amdgcn_s_barrier();
}

template <int EPI>   // 0 plain, 1 softplus, 2 softplus + row-mask zero
__global__ __launch_bounds__(512, 2) void k_gemm256(
    const u16* __restrict__ A, const u16* __restrict__ B, u16* __restrict__ C,
    const int* __restrict__ mask) {
  extern __shared__ u16 lsg[];                 // 128 KiB
  int tid = threadIdx.x, lane = tid & 63, wid = tid >> 6;
  int bm0 = (blockIdx.x >> 3) << 8;            // 64 M-tiles
  int bn0 = (blockIdx.x & 7) << 8;             // 8 N-tiles (bn = bid%8 -> XCD)
  int wr = wid >> 2, wc = wid & 3;
  int l15 = lane & 15, ko8 = (lane >> 4) * 8;
  int arow0 = wr * 64 + l15, brow0 = wc * 32 + l15;
  int lr = lane >> 3, cg = (lane & 7) ^ lr;    // inverse-swizzled source granule
  const u16* srcA = A + (size_t)(bm0 + wid * 8 + lr) * 2048 + cg * 8;
  const u16* srcB = B + (size_t)(bn0 + wid * 8 + lr) * 2048 + cg * 8;
  u16* lsu = lsg + wid * 512;                  // wave-uniform stage dest base

  fx4 acc[4][4][2] = {};                       // [quadrant][mi][ni]

  // prologue: tile0 all 4 halves + tile1 A0,B0; vmcnt(4) -> tile0 resident
  stage2(srcA, lsu + 0);                       // buf0.A h0  (t0)
  stage2(srcB, lsu + 16384);                   // buf0.B h0
  stage2(srcA + 262144, lsu + 8192);           // buf0.A h1
  stage2(srcB + 262144, lsu + 16384 + 8192);   // buf0.B h1
  stage2(srcA + 64, lsu + 32768);              // buf1.A h0  (t1)
  stage2(srcB + 64, lsu + 49152);              // buf1.B h0
  asm volatile("s_waitcnt vmcnt(4)" ::: "memory");
  __builtin_amdgcn_s_barrier();

  for (int it = 0; it < 16; it++) {
    int t1 = 2 * it + 1;
    int t2 = 2 * it + 2; if (t2 > 31) t2 = 31;   // clamped prefetch (harmless)
    int t3 = 2 * it + 3; if (t3 > 31) t3 = 31;
    // phases 1-4: compute tile 2it from buf0 (Q00,Q01,Q10,Q11)
    phase<false>(lsg, 0,            16384,        acc[0], arow0, brow0, ko8,
                 srcA + 262144 + t1 * 64, lsu + 32768 + 8192);   // stage buf1.A h1 (t1)
    phase<false>(lsg, 0,            16384 + 8192, acc[1], arow0, brow0, ko8,
                 srcB + 262144 + t1 * 64, lsu + 49152 + 8192);   // stage buf1.B h1 (t1)
    phase<false>(lsg, 8192,         16384,        acc[2], arow0, brow0, ko8,
                 srcA + t2 * 64,          lsu + 0);              // stage buf0.A h0 (t2)
    phase<true >(lsg, 8192,         16384 + 8192, acc[3], arow0, brow0, ko8,
                 srcB + t2 * 64,          lsu + 16384);          // stage buf0.B h0 (t2)
    // phases 5-8: compute tile 2it+1 from buf1
    phase<false>(lsg, 32768,        49152,        acc[0], arow0, brow0, ko8,
                 srcA + 262144 + t2 * 64, lsu + 8192);           // stage buf0.A h1 (t2)
    phase<false>(lsg, 32768,        49152 + 8192, acc[1], arow0, brow0, ko8,
                 srcB + 262144 + t2 * 64, lsu + 16384 + 8192);   // stage buf0.B h1 (t2)
    phase<false>(lsg, 32768 + 8192, 49152,        acc[2], arow0, brow0, ko8,
                 srcA + t3 * 64,          lsu + 32768);          // stage buf1.A h0 (t3)
    phase<true >(lsg, 32768 + 8192, 49152 + 8192, acc[3], arow0, brow0, ko8,
                 srcB + t3 * 64,          lsu + 49152);          // stage buf1.B h0 (t3)
  }

  // epilogue: D row=(lane>>4)*4+reg, col=lane&15 (m89-verified)
#pragma unroll
  for (int q = 0; q < 4; q++)
#pragma unroll
    for (int mi = 0; mi < 4; mi++)
#pragma unroll
      for (int ni = 0; ni < 2; ni++) {
        int gi0 = bm0 + (q >> 1) * 128 + wr * 64 + mi * 16 + (lane >> 4) * 4;
        int gj  = bn0 + (q & 1) * 128 + wc * 32 + ni * 16 + l15;
#pragma unroll
        for (int j = 0; j < 4; j++) {
          int gi = gi0 + j;
          float v = acc[q][mi][ni][j];
          if (EPI >= 1) v = softplus_f(v);
          if (EPI == 2) { if (mask[gi]) v = 0.f; }
          C[(size_t)gi * 2048 + gj] = f2bf(v);
        }
      }
}

// ---------------- s[n,h,d] = sum_k pk[n,k,h*128+d] ----------------
__global__ __launch_bounds__(512) void k_ssum(const u16* __restrict__ pk,
                                              float* __restrict__ s) {
  int nh = blockIdx.x;            // n*16+h
  int n = nh >> 4, h = nh & 15;
  __shared__ float red[32][128];
  int t = threadIdx.x;
  int d8 = (t & 15) * 8;          // 8 cols per thread
  int p = t >> 4;                 // 32 k-parts
  const u16* base = pk + (size_t)(n * 4096) * 2048 + h * 128 + d8;
  float a[8] = {};
  for (int k = p * 128; k < p * 128 + 128; k++) {
    bh8 v = *(const bh8*)(base + (size_t)k * 2048);
#pragma unroll
    for (int i = 0; i < 8; i++) a[i] += bf2f((u16)v[i]);
  }
#pragma unroll
  for (int i = 0; i < 8; i++) red[p][d8 + i] = a[i];
  __syncthreads();
  if (t < 128) {
    float sum = 0.f;
#pragma unroll
    for (int pp = 0; pp < 32; pp++) sum += red[pp][t];
    s[nh * 128 + t] = sum;
  }
}

// ---------------- kvT[n,h,e,d] = sum_k pk[k,d]*v[k,e] ----------------
__global__ __launch_bounds__(256, 1) void k_kv(const u16* __restrict__ pk,
                                               const u16* __restrict__ v,
                                               u16* __restrict__ kvT) {
  int nh = blockIdx.x;
  int n = nh >> 4, h = nh & 15;
  __shared__ u16 lsA[128 * 32];   // pk^T tile: [d][k]
  __shared__ u16 lsB[128 * 32];   // v^T tile:  [e][k]
  int tid = threadIdx.x, lane = tid & 63, wid = tid >> 6;
  int wr = wid >> 1, wc = wid & 1;
  int kk = tid >> 3;              // 0..31 (k within slab)
  int dg = (tid & 7) * 16;        // 0..112 (16 cols per thread)
  size_t rowbase = ((size_t)(n * 4096) + kk) * 2048 + h * 128 + dg;
  int r = lane & 15, ko = (lane >> 4) * 8;
  fx4 acc[4][4] = {};
  for (int k0 = 0; k0 < 4096; k0 += 32) {
    __syncthreads();
    bh8 a0 = *(const bh8*)(pk + rowbase + (size_t)k0 * 2048);
    bh8 a1 = *(const bh8*)(pk + rowbase + (size_t)k0 * 2048 + 8);
    bh8 b0 = *(const bh8*)(v + rowbase + (size_t)k0 * 2048);
    bh8 b1 = *(const bh8*)(v + rowbase + (size_t)k0 * 2048 + 8);
#pragma unroll
    for (int i = 0; i < 8; i++) {
      lsA[(dg + i) * 32 + kk] = (u16)a0[i];
      lsA[(dg + 8 + i) * 32 + kk] = (u16)a1[i];
      lsB[(dg + i) * 32 + kk] = (u16)b0[i];
      lsB[(dg + 8 + i) * 32 + kk] = (u16)b1[i];
    }
    __syncthreads();
    bh8 af[4], bfr[4];
#pragma unroll
    for (int mi = 0; mi < 4; mi++)
      af[mi] = *(const bh8*)&lsA[(wr * 64 + mi * 16 + r) * 32 + ko];
#pragma unroll
    for (int ni = 0; ni < 4; ni++)
      bfr[ni] = *(const bh8*)&lsB[(wc * 64 + ni * 16 + r) * 32 + ko];
#pragma unroll
    for (int mi = 0; mi < 4; mi++)
#pragma unroll
      for (int ni = 0; ni < 4; ni++)
        acc[mi][ni] = __builtin_amdgcn_mfma_f32_16x16x32_bf16(af[mi], bfr[ni],
                                                              acc[mi][ni], 0, 0, 0);
  }
#pragma unroll
  for (int mi = 0; mi < 4; mi++)
#pragma unroll
    for (int ni = 0; ni < 4; ni++)
#pragma unroll
      for (int j = 0; j < 4; j++) {
        int d = wr * 64 + mi * 16 + (lane >> 4) * 4 + j;
        int e = wc * 64 + ni * 16 + (lane & 15);
        kvT[((size_t)nh * 128 + e) * 128 + d] = f2bf(acc[mi][ni][j]);
      }
}

// ---------------- final: out = (pq @ kv) / (pq @ s), query-masked ----------
__global__ __launch_bounds__(256, 2) void k_att(
    const u16* __restrict__ pq, const u16* __restrict__ kvT,
    const float* __restrict__ s, const int* __restrict__ qmask,
    float* __restrict__ out) {
  int b = blockIdx.x;
  int lt = b & 31, h = (b >> 5) & 15, nb = b >> 9;
  int l0 = lt * 128;
  __shared__ u16 lsQ[128 * 128];
  __shared__ u16 lsKV[128 * 128];
  __shared__ float lsS[128];
  __shared__ float lsDen[128];
  int tid = threadIdx.x, lane = tid & 63, wid = tid >> 6;

  int row = tid >> 1, part = tid & 1;
  const u16* gq = pq + ((size_t)(nb * 4096 + l0 + row)) * 2048 + h * 128 + part * 64;
  const u16* gk = kvT + ((size_t)(nb * 16 + h) * 128 + row) * 128 + part * 64;
  int sw = (row & 7) << 3;
#pragma unroll
  for (int j = 0; j < 8; j++) {
    bh8 vq = *(const bh8*)(gq + j * 8);
    bh8 vk = *(const bh8*)(gk + j * 8);
    int ci = (part * 64 + j * 8) ^ sw;
    *(bh8*)&lsQ[row * 128 + ci] = vq;
    *(bh8*)&lsKV[row * 128 + ci] = vk;
  }
  if (tid < 128) lsS[tid] = s[(nb * 16 + h) * 128 + tid];
  __syncthreads();

  if (tid < 128) {
    int rr = tid, swr = (rr & 7) << 3;
    float dsum = 0.f;
    for (int dd = 0; dd < 128; dd++) {
      int d = (dd + rr) & 127;
      dsum += bf2f(lsQ[rr * 128 + (d ^ swr)]) * lsS[d];
    }
    lsDen[rr] = dsum;
  }
  __syncthreads();

  int wr = wid >> 1, wc = wid & 1;
  int r = lane & 15, ko = (lane >> 4) * 8;
  fx4 acc[4][4] = {};
#pragma unroll
  for (int ks = 0; ks < 4; ks++) {
    bh8 af[4], bfr[4];
#pragma unroll
    for (int mi = 0; mi < 4; mi++) {
      int rw = wr * 64 + mi * 16 + r;
      af[mi] = *(const bh8*)&lsQ[rw * 128 + ((ks * 32 + ko) ^ ((rw & 7) << 3))];
    }
#pragma unroll
    for (int ni = 0; ni < 4; ni++) {
      int rw = wc * 64 + ni * 16 + r;
      bfr[ni] = *(const bh8*)&lsKV[rw * 128 + ((ks * 32 + ko) ^ ((rw & 7) << 3))];
    }
#pragma unroll
    for (int mi = 0; mi < 4; mi++)
#pragma unroll
      for (int ni = 0; ni < 4; ni++)
        acc[mi][ni] = __builtin_amdgcn_mfma_f32_16x16x32_bf16(af[mi], bfr[ni],
                                                              acc[mi][ni], 0, 0, 0);
  }
#pragma unroll
  for (int mi = 0; mi < 4; mi++)
#pragma unroll
    for (int ni = 0; ni < 4; ni++)
#pragma unroll
      for (int j = 0; j < 4; j++) {
        int li = wr * 64 + mi * 16 + (lane >> 4) * 4 + j;
        int e = wc * 64 + ni * 16 + (lane & 15);
        int l = l0 + li;
        float v = qmask[nb * 4096 + l] ? 0.f : acc[mi][ni][j] / lsDen[li];
        out[((size_t)(nb * 4096 + l)) * 2048 + h * 128 + e] = v;
      }
}

// ---------------- launch ----------------
extern "C" void kernel_launch(void* const* d_in, const int* in_sizes, int n_in,
                              void* d_out, int out_size, void* d_ws, size_t ws_size,
                              hipStream_t stream) {
  const float* query = (const float*)d_in[0];
  const float* key   = (const float*)d_in[1];
  const float* Wq    = (const float*)d_in[2];
  const float* Wk    = (const float*)d_in[3];
  const float* Wv    = (const float*)d_in[4];
  const int* qmask   = (const int*)d_in[5];
  const int* kmask   = (const int*)d_in[6];
  float* out = (float*)d_out;
  char* ws = (char*)d_ws;

  u16* qb   = (u16*)(ws + 0);
  u16* kb   = (u16*)(ws + 67108864ull);
  u16* Wqb  = (u16*)(ws + 134217728ull);
  u16* Wkb  = (u16*)(ws + 142606336ull);
  u16* Wvb  = (u16*)(ws + 150994944ull);
  u16* pq   = (u16*)(ws + 159383552ull);
  u16* kvT  = (u16*)(ws + 226492416ull);
  float* sb = (float*)(ws + 228589568ull);
  // pk and v die before k_att -> live in d_out
  u16* pk = (u16*)d_out;
  u16* vb = (u16*)d_out + 33554432ull;

  k_cvt<<<2048, 256, 0, stream>>>(query, qb, 33554432 / 4);
  k_cvt<<<2048, 256, 0, stream>>>(key, kb, 33554432 / 4);
  k_cvt<<<512, 256, 0, stream>>>(Wq, Wqb, 4194304 / 4);
  k_cvt<<<512, 256, 0, stream>>>(Wk, Wkb, 4194304 / 4);
  k_cvt<<<512, 256, 0, stream>>>(Wv, Wvb, 4194304 / 4);

  k_gemm256<1><<<512, 512, 131072, stream>>>(qb, Wqb, pq, nullptr);
  k_gemm256<2><<<512, 512, 131072, stream>>>(kb, Wkb, pk, kmask);
  k_gemm256<0><<<512, 512, 131072, stream>>>(kb, Wvb, vb, nullptr);

  k_ssum<<<64, 512, 0, stream>>>(pk, sb);
  k_kv<<<64, 256, 0, stream>>>(pk, vb, kvT);
  k_att<<<2048, 256, 0, stream>>>(pq, kvT, sb, qmask, out);
}

// Round 3
// 953.915 us; speedup vs baseline: 2.3773x; 2.3773x over previous
//
#include <hip/hip_runtime.h>
#include <stdint.h>

typedef __attribute__((ext_vector_type(8))) short    bh8;   // 8 x bf16 (4 VGPR)
typedef __attribute__((ext_vector_type(4))) float    fx4;   // MFMA acc
typedef __attribute__((ext_vector_type(4))) float    f4v;
typedef unsigned short u16;
typedef __attribute__((ext_vector_type(4))) unsigned short u16x4;

#define DEV static __device__ __forceinline__

DEV u16 f2bf(float f) {                       // RNE fp32 -> bf16
  unsigned u = __float_as_uint(f);
  u += 0x7FFFu + ((u >> 16) & 1u);
  return (u16)(u >> 16);
}
DEV float bf2f(u16 s) { return __uint_as_float(((unsigned)s) << 16); }
DEV float softplus_f(float x) { return fmaxf(x, 0.f) + log1pf(expf(-fabsf(x))); }

DEV void gload_lds16(const u16* g, u16* l) {  // 16B/lane async global->LDS
  __builtin_amdgcn_global_load_lds(
      (const __attribute__((address_space(1))) unsigned int*)g,
      (__attribute__((address_space(3))) unsigned int*)l, 16, 0, 0);
}
DEV void stage2(const u16* s, u16* d) {       // one 256-row x 64-col half-tile piece
  gload_lds16(s, d);
  gload_lds16(s + 131072, d + 4096);          // +64 rows (ld = 2048)
}

// ---------------- fp32 -> bf16 convert (vectorized) ----------------
__global__ __launch_bounds__(256) void k_cvt(const float* __restrict__ in,
                                             u16* __restrict__ out, int n4) {
  int i = blockIdx.x * 256 + threadIdx.x;
  int stride = gridDim.x * 256;
  for (; i < n4; i += stride) {
    f4v v = ((const f4v*)in)[i];
    u16x4 o;
    o.x = f2bf(v.x); o.y = f2bf(v.y); o.z = f2bf(v.z); o.w = f2bf(v.w);
    ((u16x4*)out)[i] = o;
  }
}

// ================= 256x256 8-phase GEMM (T2+T3+T4+T5) =================
// C[i,j] = sum_k A[i,k]*B[j,k]; M=16384, N=2048, K=2048 hardcoded.
// LDS (u16 idx): buf0.A [0,16384) buf0.B [16384,32768)
//                buf1.A [32768,49152) buf1.B [49152,65536)
// Tiles 256r x 64c row-major; ds_read XOR-swizzle idx ^= (row&7)<<3;
// staging = linear LDS dest + inverse-swizzled global source (rule #21).
// ALL accumulators are individually named scalars (rule #20: no aggregates).

#define MM(a, b, c) __builtin_amdgcn_mfma_f32_16x16x32_bf16(a, b, c, 0, 0, 0)
#define LD(BASE, RR, KS) \
  (*(const bh8*)&lsg[(BASE) + (RR) * 64 + ((((KS) * 32) + ko8) ^ swz)])

#define DECLQ(Q)                                                         \
  fx4 acc##Q##00 = {}, acc##Q##01 = {}, acc##Q##10 = {}, acc##Q##11 = {}, \
      acc##Q##20 = {}, acc##Q##21 = {}, acc##Q##30 = {}, acc##Q##31 = {}

#define WL asm volatile("s_waitcnt lgkmcnt(0)")
#define WV asm volatile("s_waitcnt vmcnt(4)"); asm volatile("s_waitcnt lgkmcnt(0)")

#define PHASE(Q, ABASE, BBASE, WAITS, SSRC, SDST) {                           \
  bh8 a00 = LD(ABASE, arow0,      0), a01 = LD(ABASE, arow0,      1);         \
  bh8 a10 = LD(ABASE, arow0 + 16, 0), a11 = LD(ABASE, arow0 + 16, 1);         \
  bh8 a20 = LD(ABASE, arow0 + 32, 0), a21 = LD(ABASE, arow0 + 32, 1);         \
  bh8 a30 = LD(ABASE, arow0 + 48, 0), a31 = LD(ABASE, arow0 + 48, 1);         \
  bh8 b00 = LD(BBASE, brow0,      0), b01 = LD(BBASE, brow0,      1);         \
  bh8 b10 = LD(BBASE, brow0 + 16, 0), b11 = LD(BBASE, brow0 + 16, 1);         \
  stage2(SSRC, SDST);                                                         \
  __builtin_amdgcn_s_barrier();                                               \
  __builtin_amdgcn_s_setprio(1);                                              \
  acc##Q##00 = MM(a00, b00, acc##Q##00); acc##Q##01 = MM(a00, b10, acc##Q##01); \
  acc##Q##10 = MM(a10, b00, acc##Q##10); acc##Q##11 = MM(a10, b10, acc##Q##11); \
  acc##Q##20 = MM(a20, b00, acc##Q##20); acc##Q##21 = MM(a20, b10, acc##Q##21); \
  acc##Q##30 = MM(a30, b00, acc##Q##30); acc##Q##31 = MM(a30, b10, acc##Q##31); \
  acc##Q##00 = MM(a01, b01, acc##Q##00); acc##Q##01 = MM(a01, b11, acc##Q##01); \
  acc##Q##10 = MM(a11, b01, acc##Q##10); acc##Q##11 = MM(a11, b11, acc##Q##11); \
  acc##Q##20 = MM(a21, b01, acc##Q##20); acc##Q##21 = MM(a21, b11, acc##Q##21); \
  acc##Q##30 = MM(a31, b01, acc##Q##30); acc##Q##31 = MM(a31, b11, acc##Q##31); \
  __builtin_amdgcn_s_setprio(0);                                              \
  WAITS;                                                                      \
  __builtin_amdgcn_s_barrier();                                               \
}

// store one 16x16 fragment (4 rows x-w), with epilogue EPI
#define STE(AC, EL, JOFF) {                                                   \
  float v = AC.EL;                                                            \
  if (EPI >= 1) v = softplus_f(v);                                            \
  if (EPI == 2) { if (mask[gi0 + JOFF]) v = 0.f; }                            \
  C[(size_t)(gi0 + JOFF) * 2048 + gj] = f2bf(v);                              \
}
#define ST1(AC, QR, QC, MI, NI) {                                             \
  int gi0 = bm0 + (QR) * 128 + wr * 64 + (MI) * 16 + (lane >> 4) * 4;         \
  int gj  = bn0 + (QC) * 128 + wc * 32 + (NI) * 16 + l15;                     \
  STE(AC, x, 0) STE(AC, y, 1) STE(AC, z, 2) STE(AC, w, 3)                     \
}
#define EPIQ(Q, QR, QC)                                                       \
  ST1(acc##Q##00, QR, QC, 0, 0) ST1(acc##Q##01, QR, QC, 0, 1)                 \
  ST1(acc##Q##10, QR, QC, 1, 0) ST1(acc##Q##11, QR, QC, 1, 1)                 \
  ST1(acc##Q##20, QR, QC, 2, 0) ST1(acc##Q##21, QR, QC, 2, 1)                 \
  ST1(acc##Q##30, QR, QC, 3, 0) ST1(acc##Q##31, QR, QC, 3, 1)

template <int EPI>   // 0 plain, 1 softplus, 2 softplus + row-mask zero
__global__ __launch_bounds__(512, 2) void k_gemm256(
    const u16* __restrict__ A, const u16* __restrict__ B, u16* __restrict__ C,
    const int* __restrict__ mask) {
  extern __shared__ u16 lsg[];                 // 128 KiB dynamic
  int tid = threadIdx.x, lane = tid & 63, wid = tid >> 6;
  int bm0 = (blockIdx.x >> 3) << 8;            // 64 M-tiles
  int bn0 = (blockIdx.x & 7) << 8;             // 8 N-tiles (bid%8 -> XCD locality)
  int wr = wid >> 2, wc = wid & 3;
  int l15 = lane & 15, ko8 = (lane >> 4) * 8;
  int swz = (l15 & 7) << 3;
  int arow0 = wr * 64 + l15, brow0 = wc * 32 + l15;
  int lr = lane >> 3, cg = (lane & 7) ^ lr;    // inverse-swizzled source granule
  const u16* srcA = A + (size_t)(bm0 + wid * 8 + lr) * 2048 + cg * 8;
  const u16* srcB = B + (size_t)(bn0 + wid * 8 + lr) * 2048 + cg * 8;
  u16* lsu = lsg + wid * 512;                  // wave-uniform stage dest base

  DECLQ(0); DECLQ(1); DECLQ(2); DECLQ(3);

  // prologue: tile0 all 4 halves + tile1 A-h0,B-h0; vmcnt(4) -> tile0 resident
  stage2(srcA, lsu + 0);                       // buf0.A h0  (t0)
  stage2(srcB, lsu + 16384);                   // buf0.B h0
  stage2(srcA + 262144, lsu + 8192);           // buf0.A h1
  stage2(srcB + 262144, lsu + 16384 + 8192);   // buf0.B h1
  stage2(srcA + 64, lsu + 32768);              // buf1.A h0  (t1)
  stage2(srcB + 64, lsu + 49152);              // buf1.B h0
  asm volatile("s_waitcnt vmcnt(4)");
  __builtin_amdgcn_s_barrier();

  for (int it = 0; it < 16; it++) {
    int t1 = 2 * it + 1;
    int t2 = 2 * it + 2; if (t2 > 31) t2 = 31;   // clamped prefetch (dup, unread)
    int t3 = 2 * it + 3; if (t3 > 31) t3 = 31;
    // phases 1-4: compute tile 2it from buf0 (quadrants 00,01,10,11)
    PHASE(0, 0,            16384,        WL, srcA + 262144 + t1 * 64, lsu + 32768 + 8192)
    PHASE(1, 0,            16384 + 8192, WL, srcB + 262144 + t1 * 64, lsu + 49152 + 8192)
    PHASE(2, 8192,         16384,        WL, srcA + t2 * 64,          lsu + 0)
    PHASE(3, 8192,         16384 + 8192, WV, srcB + t2 * 64,          lsu + 16384)
    // phases 5-8: compute tile 2it+1 from buf1
    PHASE(0, 32768,        49152,        WL, srcA + 262144 + t2 * 64, lsu + 8192)
    PHASE(1, 32768,        49152 + 8192, WL, srcB + 262144 + t2 * 64, lsu + 16384 + 8192)
    PHASE(2, 32768 + 8192, 49152,        WL, srcA + t3 * 64,          lsu + 32768)
    PHASE(3, 32768 + 8192, 49152 + 8192, WV, srcB + t3 * 64,          lsu + 49152)
  }

  // epilogue: D row=(lane>>4)*4+reg, col=lane&15 (m89-verified)
  EPIQ(0, 0, 0)
  EPIQ(1, 0, 1)
  EPIQ(2, 1, 0)
  EPIQ(3, 1, 1)
}

// ---------------- s[n,h,d] = sum_k pk[n,k,h*128+d] ----------------
__global__ __launch_bounds__(512) void k_ssum(const u16* __restrict__ pk,
                                              float* __restrict__ s) {
  int nh = blockIdx.x;            // n*16+h
  int n = nh >> 4, h = nh & 15;
  __shared__ float red[32][128];
  int t = threadIdx.x;
  int d8 = (t & 15) * 8;          // 8 cols per thread
  int p = t >> 4;                 // 32 k-parts
  const u16* base = pk + (size_t)(n * 4096) * 2048 + h * 128 + d8;
  float a[8] = {};
  for (int k = p * 128; k < p * 128 + 128; k++) {
    bh8 v = *(const bh8*)(base + (size_t)k * 2048);
#pragma unroll
    for (int i = 0; i < 8; i++) a[i] += bf2f((u16)v[i]);
  }
#pragma unroll
  for (int i = 0; i < 8; i++) red[p][d8 + i] = a[i];
  __syncthreads();
  if (t < 128) {
    float sum = 0.f;
#pragma unroll
    for (int pp = 0; pp < 32; pp++) sum += red[pp][t];
    s[nh * 128 + t] = sum;
  }
}

// ---------------- kvT[n,h,e,d] = sum_k pk[k,d]*v[k,e] ----------------
__global__ __launch_bounds__(256, 1) void k_kv(const u16* __restrict__ pk,
                                               const u16* __restrict__ v,
                                               u16* __restrict__ kvT) {
  int nh = blockIdx.x;
  int n = nh >> 4, h = nh & 15;
  __shared__ u16 lsA[128 * 32];   // pk^T tile: [d][k]
  __shared__ u16 lsB[128 * 32];   // v^T tile:  [e][k]
  int tid = threadIdx.x, lane = tid & 63, wid = tid >> 6;
  int wr = wid >> 1, wc = wid & 1;
  int kk = tid >> 3;              // 0..31 (k within slab)
  int dg = (tid & 7) * 16;        // 0..112 (16 cols per thread)
  size_t rowbase = ((size_t)(n * 4096) + kk) * 2048 + h * 128 + dg;
  int r = lane & 15, ko = (lane >> 4) * 8;
  fx4 acc[4][4] = {};
  for (int k0 = 0; k0 < 4096; k0 += 32) {
    __syncthreads();
    bh8 a0 = *(const bh8*)(pk + rowbase + (size_t)k0 * 2048);
    bh8 a1 = *(const bh8*)(pk + rowbase + (size_t)k0 * 2048 + 8);
    bh8 b0 = *(const bh8*)(v + rowbase + (size_t)k0 * 2048);
    bh8 b1 = *(const bh8*)(v + rowbase + (size_t)k0 * 2048 + 8);
#pragma unroll
    for (int i = 0; i < 8; i++) {
      lsA[(dg + i) * 32 + kk] = (u16)a0[i];
      lsA[(dg + 8 + i) * 32 + kk] = (u16)a1[i];
      lsB[(dg + i) * 32 + kk] = (u16)b0[i];
      lsB[(dg + 8 + i) * 32 + kk] = (u16)b1[i];
    }
    __syncthreads();
    bh8 af[4], bfr[4];
#pragma unroll
    for (int mi = 0; mi < 4; mi++)
      af[mi] = *(const bh8*)&lsA[(wr * 64 + mi * 16 + r) * 32 + ko];
#pragma unroll
    for (int ni = 0; ni < 4; ni++)
      bfr[ni] = *(const bh8*)&lsB[(wc * 64 + ni * 16 + r) * 32 + ko];
#pragma unroll
    for (int mi = 0; mi < 4; mi++)
#pragma unroll
      for (int ni = 0; ni < 4; ni++)
        acc[mi][ni] = __builtin_amdgcn_mfma_f32_16x16x32_bf16(af[mi], bfr[ni],
                                                              acc[mi][ni], 0, 0, 0);
  }
#pragma unroll
  for (int mi = 0; mi < 4; mi++)
#pragma unroll
    for (int ni = 0; ni < 4; ni++)
#pragma unroll
      for (int j = 0; j < 4; j++) {
        int d = wr * 64 + mi * 16 + (lane >> 4) * 4 + j;
        int e = wc * 64 + ni * 16 + (lane & 15);
        kvT[((size_t)nh * 128 + e) * 128 + d] = f2bf(acc[mi][ni][j]);
      }
}

// ---------------- final: out = (pq @ kv) / (pq @ s), query-masked ----------
__global__ __launch_bounds__(256, 2) void k_att(
    const u16* __restrict__ pq, const u16* __restrict__ kvT,
    const float* __restrict__ s, const int* __restrict__ qmask,
    float* __restrict__ out) {
  int b = blockIdx.x;
  int lt = b & 31, h = (b >> 5) & 15, nb = b >> 9;
  int l0 = lt * 128;
  __shared__ u16 lsQ[128 * 128];
  __shared__ u16 lsKV[128 * 128];
  __shared__ float lsS[128];
  __shared__ float lsDen[128];
  int tid = threadIdx.x, lane = tid & 63, wid = tid >> 6;

  int row = tid >> 1, part = tid & 1;
  const u16* gq = pq + ((size_t)(nb * 4096 + l0 + row)) * 2048 + h * 128 + part * 64;
  const u16* gk = kvT + ((size_t)(nb * 16 + h) * 128 + row) * 128 + part * 64;
  int sw = (row & 7) << 3;
#pragma unroll
  for (int j = 0; j < 8; j++) {
    bh8 vq = *(const bh8*)(gq + j * 8);
    bh8 vk = *(const bh8*)(gk + j * 8);
    int ci = (part * 64 + j * 8) ^ sw;
    *(bh8*)&lsQ[row * 128 + ci] = vq;
    *(bh8*)&lsKV[row * 128 + ci] = vk;
  }
  if (tid < 128) lsS[tid] = s[(nb * 16 + h) * 128 + tid];
  __syncthreads();

  if (tid < 128) {
    int rr = tid, swr = (rr & 7) << 3;
    float dsum = 0.f;
    for (int dd = 0; dd < 128; dd++) {
      int d = (dd + rr) & 127;
      dsum += bf2f(lsQ[rr * 128 + (d ^ swr)]) * lsS[d];
    }
    lsDen[rr] = dsum;
  }
  __syncthreads();

  int wr = wid >> 1, wc = wid & 1;
  int r = lane & 15, ko = (lane >> 4) * 8;
  fx4 acc[4][4] = {};
#pragma unroll
  for (int ks = 0; ks < 4; ks++) {
    bh8 af[4], bfr[4];
#pragma unroll
    for (int mi = 0; mi < 4; mi++) {
      int rw = wr * 64 + mi * 16 + r;
      af[mi] = *(const bh8*)&lsQ[rw * 128 + ((ks * 32 + ko) ^ ((rw & 7) << 3))];
    }
#pragma unroll
    for (int ni = 0; ni < 4; ni++) {
      int rw = wc * 64 + ni * 16 + r;
      bfr[ni] = *(const bh8*)&lsKV[rw * 128 + ((ks * 32 + ko) ^ ((rw & 7) << 3))];
    }
#pragma unroll
    for (int mi = 0; mi < 4; mi++)
#pragma unroll
      for (int ni = 0; ni < 4; ni++)
        acc[mi][ni] = __builtin_amdgcn_mfma_f32_16x16x32_bf16(af[mi], bfr[ni],
                                                              acc[mi][ni], 0, 0, 0);
  }
#pragma unroll
  for (int mi = 0; mi < 4; mi++)
#pragma unroll
    for (int ni = 0; ni < 4; ni++)
#pragma unroll
      for (int j = 0; j < 4; j++) {
        int li = wr * 64 + mi * 16 + (lane >> 4) * 4 + j;
        int e = wc * 64 + ni * 16 + (lane & 15);
        int l = l0 + li;
        float v = qmask[nb * 4096 + l] ? 0.f : acc[mi][ni][j] / lsDen[li];
        out[((size_t)(nb * 4096 + l)) * 2048 + h * 128 + e] = v;
      }
}

// ---------------- launch ----------------
extern "C" void kernel_launch(void* const* d_in, const int* in_sizes, int n_in,
                              void* d_out, int out_size, void* d_ws, size_t ws_size,
                              hipStream_t stream) {
  const float* query = (const float*)d_in[0];
  const float* key   = (const float*)d_in[1];
  const float* Wq    = (const float*)d_in[2];
  const float* Wk    = (const float*)d_in[3];
  const float* Wv    = (const float*)d_in[4];
  const int* qmask   = (const int*)d_in[5];
  const int* kmask   = (const int*)d_in[6];
  float* out = (float*)d_out;
  char* ws = (char*)d_ws;

  u16* qb   = (u16*)(ws + 0);
  u16* kb   = (u16*)(ws + 67108864ull);
  u16* Wqb  = (u16*)(ws + 134217728ull);
  u16* Wkb  = (u16*)(ws + 142606336ull);
  u16* Wvb  = (u16*)(ws + 150994944ull);
  u16* pq   = (u16*)(ws + 159383552ull);
  u16* kvT  = (u16*)(ws + 226492416ull);
  float* sb = (float*)(ws + 228589568ull);
  // pk and v die before k_att -> live in d_out
  u16* pk = (u16*)d_out;
  u16* vb = (u16*)d_out + 33554432ull;

  k_cvt<<<2048, 256, 0, stream>>>(query, qb, 33554432 / 4);
  k_cvt<<<2048, 256, 0, stream>>>(key, kb, 33554432 / 4);
  k_cvt<<<512, 256, 0, stream>>>(Wq, Wqb, 4194304 / 4);
  k_cvt<<<512, 256, 0, stream>>>(Wk, Wkb, 4194304 / 4);
  k_cvt<<<512, 256, 0, stream>>>(Wv, Wvb, 4194304 / 4);

  k_gemm256<1><<<512, 512, 131072, stream>>>(qb, Wqb, pq, nullptr);
  k_gemm256<2><<<512, 512, 131072, stream>>>(kb, Wkb, pk, kmask);
  k_gemm256<0><<<512, 512, 131072, stream>>>(kb, Wvb, vb, nullptr);

  k_ssum<<<64, 512, 0, stream>>>(pk, sb);
  k_kv<<<64, 256, 0, stream>>>(pk, vb, kvT);
  k_att<<<2048, 256, 0, stream>>>(pq, kvT, sb, qmask, out);
}

// Round 4
// 920.712 us; speedup vs baseline: 2.4630x; 1.0361x over previous
//
#include <hip/hip_runtime.h>
#include <stdint.h>

typedef __attribute__((ext_vector_type(8))) short    bh8;   // 8 x bf16 (4 VGPR)
typedef __attribute__((ext_vector_type(4))) float    fx4;   // MFMA acc
typedef __attribute__((ext_vector_type(4))) float    f4v;
typedef unsigned short u16;
typedef __attribute__((ext_vector_type(4))) unsigned short u16x4;

#define DEV static __device__ __forceinline__

DEV u16 f2bf(float f) {                       // RNE fp32 -> bf16
  unsigned u = __float_as_uint(f);
  u += 0x7FFFu + ((u >> 16) & 1u);
  return (u16)(u >> 16);
}
DEV float bf2f(u16 s) { return __uint_as_float(((unsigned)s) << 16); }
DEV float softplus_f(float x) { return fmaxf(x, 0.f) + log1pf(expf(-fabsf(x))); }

DEV void gload_lds16(const u16* g, u16* l) {  // 16B/lane async global->LDS
  __builtin_amdgcn_global_load_lds(
      (const __attribute__((address_space(1))) unsigned int*)g,
      (__attribute__((address_space(3))) unsigned int*)l, 16, 0, 0);
}
DEV void stage2(const u16* s, u16* d) {       // one 128-row piece of a half-tile
  gload_lds16(s, d);
  gload_lds16(s + 131072, d + 4096);          // +64 rows (ld = 2048)
}

// ---------------- fp32 -> bf16 convert (vectorized) ----------------
__global__ __launch_bounds__(256) void k_cvt(const float* __restrict__ in,
                                             u16* __restrict__ out, int n4) {
  int i = blockIdx.x * 256 + threadIdx.x;
  int stride = gridDim.x * 256;
  for (; i < n4; i += stride) {
    f4v v = ((const f4v*)in)[i];
    u16x4 o;
    o.x = f2bf(v.x); o.y = f2bf(v.y); o.z = f2bf(v.z); o.w = f2bf(v.w);
    ((u16x4*)out)[i] = o;
  }
}

// ================= 256x256 8-phase GEMM (T2+T3+T4+T5) =================
// C[i,j] = sum_k A[i,k]*B[j,k]; M=16384, N=2048, K=2048 hardcoded.
// LDS (u16 idx): buf0.A h0=0 h1=8192 | buf0.B h0=16384 h1=24576
//                buf1.A h0=32768 h1=40960 | buf1.B h0=49152 h1=57344
// Tiles 256r x 64c row-major; ds_read XOR-swizzle idx ^= (row&7)<<3;
// staging = linear LDS dest + inverse-swizzled global source (rule #21).
// Fragment-dedup phase schedule: per K-tile {A0+B0+B1 (16 rd), 0, A1 (8 rd), 0}
// -> 24 ds_read_b128 per wave per K-tile (was 48). All acc/frags named (rule #20).

#define MM(a, b, c) __builtin_amdgcn_mfma_f32_16x16x32_bf16(a, b, c, 0, 0, 0)
#define LD(BASE, RR, KS) \
  (*(const bh8*)&lsg[(BASE) + (RR) * 64 + ((((KS) * 32) + ko8) ^ swz)])

#define DECLQ(Q)                                                          \
  fx4 acc##Q##00 = {}, acc##Q##01 = {}, acc##Q##10 = {}, acc##Q##11 = {}, \
      acc##Q##20 = {}, acc##Q##21 = {}, acc##Q##30 = {}, acc##Q##31 = {}

#define WL asm volatile("s_waitcnt lgkmcnt(0)")
#define WV asm volatile("s_waitcnt vmcnt(4)"); asm volatile("s_waitcnt lgkmcnt(0)")

#define LDA8(AB)                                                \
  a_00 = LD(AB, arow0,      0); a_01 = LD(AB, arow0,      1);   \
  a_10 = LD(AB, arow0 + 16, 0); a_11 = LD(AB, arow0 + 16, 1);   \
  a_20 = LD(AB, arow0 + 32, 0); a_21 = LD(AB, arow0 + 32, 1);   \
  a_30 = LD(AB, arow0 + 48, 0); a_31 = LD(AB, arow0 + 48, 1);

#define LDB4(BN, BB)                                                        \
  b##BN##_00 = LD(BB, brow0,      0); b##BN##_01 = LD(BB, brow0,      1);   \
  b##BN##_10 = LD(BB, brow0 + 16, 0); b##BN##_11 = LD(BB, brow0 + 16, 1);

#define MFMA16(Q, BN)                                                           \
  acc##Q##00 = MM(a_00, b##BN##_00, acc##Q##00);                                \
  acc##Q##01 = MM(a_00, b##BN##_10, acc##Q##01);                                \
  acc##Q##10 = MM(a_10, b##BN##_00, acc##Q##10);                                \
  acc##Q##11 = MM(a_10, b##BN##_10, acc##Q##11);                                \
  acc##Q##20 = MM(a_20, b##BN##_00, acc##Q##20);                                \
  acc##Q##21 = MM(a_20, b##BN##_10, acc##Q##21);                                \
  acc##Q##30 = MM(a_30, b##BN##_00, acc##Q##30);                                \
  acc##Q##31 = MM(a_30, b##BN##_10, acc##Q##31);                                \
  acc##Q##00 = MM(a_01, b##BN##_01, acc##Q##00);                                \
  acc##Q##01 = MM(a_01, b##BN##_11, acc##Q##01);                                \
  acc##Q##10 = MM(a_11, b##BN##_01, acc##Q##10);                                \
  acc##Q##11 = MM(a_11, b##BN##_11, acc##Q##11);                                \
  acc##Q##20 = MM(a_21, b##BN##_01, acc##Q##20);                                \
  acc##Q##21 = MM(a_21, b##BN##_11, acc##Q##21);                                \
  acc##Q##30 = MM(a_31, b##BN##_01, acc##Q##30);                                \
  acc##Q##31 = MM(a_31, b##BN##_11, acc##Q##31);

// LOADS go in __VA_ARGS__ (may be empty)
#define PHASE(Q, BN, WAITS, SSRC, SDST, ...) {  \
  __VA_ARGS__                                   \
  stage2(SSRC, SDST);                           \
  __builtin_amdgcn_s_barrier();                 \
  __builtin_amdgcn_s_setprio(1);                \
  MFMA16(Q, BN)                                 \
  __builtin_amdgcn_s_setprio(0);                \
  WAITS;                                        \
  __builtin_amdgcn_s_barrier();                 \
}

// store one 16x16 fragment (4 rows x-w), with epilogue EPI
#define STE(AC, EL, JOFF) {                                                   \
  float v = AC.EL;                                                            \
  if (EPI >= 1) v = softplus_f(v);                                            \
  if (EPI == 2) { if (mask[gi0 + JOFF]) v = 0.f; }                            \
  C[(size_t)(gi0 + JOFF) * 2048 + gj] = f2bf(v);                              \
}
#define ST1(AC, QR, QC, MI, NI) {                                             \
  int gi0 = bm0 + (QR) * 128 + wr * 64 + (MI) * 16 + (lane >> 4) * 4;         \
  int gj  = bn0 + (QC) * 128 + wc * 32 + (NI) * 16 + l15;                     \
  STE(AC, x, 0) STE(AC, y, 1) STE(AC, z, 2) STE(AC, w, 3)                     \
}
#define EPIQ(Q, QR, QC)                                                       \
  ST1(acc##Q##00, QR, QC, 0, 0) ST1(acc##Q##01, QR, QC, 0, 1)                 \
  ST1(acc##Q##10, QR, QC, 1, 0) ST1(acc##Q##11, QR, QC, 1, 1)                 \
  ST1(acc##Q##20, QR, QC, 2, 0) ST1(acc##Q##21, QR, QC, 2, 1)                 \
  ST1(acc##Q##30, QR, QC, 3, 0) ST1(acc##Q##31, QR, QC, 3, 1)

template <int EPI>   // 0 plain, 1 softplus, 2 softplus + row-mask zero
__global__ __launch_bounds__(512, 2) void k_gemm256(
    const u16* __restrict__ A, const u16* __restrict__ B, u16* __restrict__ C,
    const int* __restrict__ mask) {
  extern __shared__ u16 lsg[];                 // 128 KiB dynamic
  int tid = threadIdx.x, lane = tid & 63, wid = tid >> 6;
  int bm0 = (blockIdx.x >> 3) << 8;            // 64 M-tiles
  int bn0 = (blockIdx.x & 7) << 8;             // 8 N-tiles (bid%8 -> XCD locality)
  int wr = wid >> 2, wc = wid & 3;
  int l15 = lane & 15, ko8 = (lane >> 4) * 8;
  int swz = (l15 & 7) << 3;
  int arow0 = wr * 64 + l15, brow0 = wc * 32 + l15;
  int lr = lane >> 3, cg = (lane & 7) ^ lr;    // inverse-swizzled source granule
  const u16* srcA = A + (size_t)(bm0 + wid * 8 + lr) * 2048 + cg * 8;
  const u16* srcB = B + (size_t)(bn0 + wid * 8 + lr) * 2048 + cg * 8;
  u16* lsu = lsg + wid * 512;                  // wave-uniform stage dest base

  DECLQ(0); DECLQ(1); DECLQ(2); DECLQ(3);
  bh8 a_00 = {}, a_01 = {}, a_10 = {}, a_11 = {},
      a_20 = {}, a_21 = {}, a_30 = {}, a_31 = {};
  bh8 b0_00 = {}, b0_01 = {}, b0_10 = {}, b0_11 = {};
  bh8 b1_00 = {}, b1_01 = {}, b1_10 = {}, b1_11 = {};

  // prologue: tile0 all 4 halves + tile1 A-h0,B-h0; vmcnt(4) -> tile0 resident
  stage2(srcA, lsu + 0);                       // buf0.A h0  (t0)
  stage2(srcB, lsu + 16384);                   // buf0.B h0
  stage2(srcA + 262144, lsu + 8192);           // buf0.A h1
  stage2(srcB + 262144, lsu + 24576);          // buf0.B h1
  stage2(srcA + 64, lsu + 32768);              // buf1.A h0  (t1)
  stage2(srcB + 64, lsu + 49152);              // buf1.B h0
  asm volatile("s_waitcnt vmcnt(4)");
  __builtin_amdgcn_s_barrier();

  for (int it = 0; it < 16; it++) {
    int t1 = 2 * it + 1;
    int t2 = 2 * it + 2; if (t2 > 31) t2 = 31;   // clamped prefetch (dup, unread)
    int t3 = 2 * it + 3; if (t3 > 31) t3 = 31;
    // phases 1-4: tile 2it from buf0.  Quadrant key: 0=(A0,B0) 1=(A0,B1)
    // 3=(A1,B1) 2=(A1,B0).  Reads per phase: {16, 0, 8, 0}.
    PHASE(0, 0, WL, srcA + 262144 + t1 * 64, lsu + 40960,
          LDA8(0) LDB4(0, 16384) LDB4(1, 24576))       // stage buf1.A h1 (t1)
    PHASE(1, 1, WL, srcB + 262144 + t1 * 64, lsu + 57344, )  // buf1.B h1 (t1)
    PHASE(3, 1, WL, srcA + t2 * 64, lsu + 0,
          LDA8(8192))                                   // buf0.A h0 (t2)
    PHASE(2, 0, WV, srcB + t2 * 64, lsu + 16384, )      // buf0.B h0 (t2)
    // phases 5-8: tile 2it+1 from buf1
    PHASE(0, 0, WL, srcA + 262144 + t2 * 64, lsu + 8192,
          LDA8(32768) LDB4(0, 49152) LDB4(1, 57344))    // buf0.A h1 (t2)
    PHASE(1, 1, WL, srcB + 262144 + t2 * 64, lsu + 24576, ) // buf0.B h1 (t2)
    PHASE(3, 1, WL, srcA + t3 * 64, lsu + 32768,
          LDA8(40960))                                  // buf1.A h0 (t3)
    PHASE(2, 0, WV, srcB + t3 * 64, lsu + 49152, )      // buf1.B h0 (t3)
  }

  // epilogue: D row=(lane>>4)*4+reg, col=lane&15 (m89-verified)
  EPIQ(0, 0, 0)
  EPIQ(1, 0, 1)
  EPIQ(2, 1, 0)
  EPIQ(3, 1, 1)
}

// ---------------- s[n,h,d] = sum_k pk[n,k,h*128+d] ----------------
__global__ __launch_bounds__(512) void k_ssum(const u16* __restrict__ pk,
                                              float* __restrict__ s) {
  int nh = blockIdx.x;            // n*16+h
  int n = nh >> 4, h = nh & 15;
  __shared__ float red[32][128];
  int t = threadIdx.x;
  int d8 = (t & 15) * 8;          // 8 cols per thread
  int p = t >> 4;                 // 32 k-parts
  const u16* base = pk + (size_t)(n * 4096) * 2048 + h * 128 + d8;
  float a[8] = {};
  for (int k = p * 128; k < p * 128 + 128; k++) {
    bh8 v = *(const bh8*)(base + (size_t)k * 2048);
#pragma unroll
    for (int i = 0; i < 8; i++) a[i] += bf2f((u16)v[i]);
  }
#pragma unroll
  for (int i = 0; i < 8; i++) red[p][d8 + i] = a[i];
  __syncthreads();
  if (t < 128) {
    float sum = 0.f;
#pragma unroll
    for (int pp = 0; pp < 32; pp++) sum += red[pp][t];
    s[nh * 128 + t] = sum;
  }
}

// ---------------- kvT[n,h,e,d] = sum_k pk[k,d]*v[k,e] ----------------
__global__ __launch_bounds__(256, 1) void k_kv(const u16* __restrict__ pk,
                                               const u16* __restrict__ v,
                                               u16* __restrict__ kvT) {
  int nh = blockIdx.x;
  int n = nh >> 4, h = nh & 15;
  __shared__ u16 lsA[128 * 32];   // pk^T tile: [d][k]
  __shared__ u16 lsB[128 * 32];   // v^T tile:  [e][k]
  int tid = threadIdx.x, lane = tid & 63, wid = tid >> 6;
  int wr = wid >> 1, wc = wid & 1;
  int kk = tid >> 3;              // 0..31 (k within slab)
  int dg = (tid & 7) * 16;        // 0..112 (16 cols per thread)
  size_t rowbase = ((size_t)(n * 4096) + kk) * 2048 + h * 128 + dg;
  int r = lane & 15, ko = (lane >> 4) * 8;
  fx4 acc[4][4] = {};
  for (int k0 = 0; k0 < 4096; k0 += 32) {
    __syncthreads();
    bh8 a0 = *(const bh8*)(pk + rowbase + (size_t)k0 * 2048);
    bh8 a1 = *(const bh8*)(pk + rowbase + (size_t)k0 * 2048 + 8);
    bh8 b0 = *(const bh8*)(v + rowbase + (size_t)k0 * 2048);
    bh8 b1 = *(const bh8*)(v + rowbase + (size_t)k0 * 2048 + 8);
#pragma unroll
    for (int i = 0; i < 8; i++) {
      lsA[(dg + i) * 32 + kk] = (u16)a0[i];
      lsA[(dg + 8 + i) * 32 + kk] = (u16)a1[i];
      lsB[(dg + i) * 32 + kk] = (u16)b0[i];
      lsB[(dg + 8 + i) * 32 + kk] = (u16)b1[i];
    }
    __syncthreads();
    bh8 af[4], bfr[4];
#pragma unroll
    for (int mi = 0; mi < 4; mi++)
      af[mi] = *(const bh8*)&lsA[(wr * 64 + mi * 16 + r) * 32 + ko];
#pragma unroll
    for (int ni = 0; ni < 4; ni++)
      bfr[ni] = *(const bh8*)&lsB[(wc * 64 + ni * 16 + r) * 32 + ko];
#pragma unroll
    for (int mi = 0; mi < 4; mi++)
#pragma unroll
      for (int ni = 0; ni < 4; ni++)
        acc[mi][ni] = __builtin_amdgcn_mfma_f32_16x16x32_bf16(af[mi], bfr[ni],
                                                              acc[mi][ni], 0, 0, 0);
  }
#pragma unroll
  for (int mi = 0; mi < 4; mi++)
#pragma unroll
    for (int ni = 0; ni < 4; ni++)
#pragma unroll
      for (int j = 0; j < 4; j++) {
        int d = wr * 64 + mi * 16 + (lane >> 4) * 4 + j;
        int e = wc * 64 + ni * 16 + (lane & 15);
        kvT[((size_t)nh * 128 + e) * 128 + d] = f2bf(acc[mi][ni][j]);
      }
}

// ---------------- final: out = (pq @ kv) / (pq @ s), query-masked ----------
__global__ __launch_bounds__(256, 2) void k_att(
    const u16* __restrict__ pq, const u16* __restrict__ kvT,
    const float* __restrict__ s, const int* __restrict__ qmask,
    float* __restrict__ out) {
  int b = blockIdx.x;
  int lt = b & 31, h = (b >> 5) & 15, nb = b >> 9;
  int l0 = lt * 128;
  __shared__ u16 lsQ[128 * 128];
  __shared__ u16 lsKV[128 * 128];
  __shared__ float lsS[128];
  __shared__ float lsDen[128];
  int tid = threadIdx.x, lane = tid & 63, wid = tid >> 6;

  int row = tid >> 1, part = tid & 1;
  const u16* gq = pq + ((size_t)(nb * 4096 + l0 + row)) * 2048 + h * 128 + part * 64;
  const u16* gk = kvT + ((size_t)(nb * 16 + h) * 128 + row) * 128 + part * 64;
  int sw = (row & 7) << 3;
#pragma unroll
  for (int j = 0; j < 8; j++) {
    bh8 vq = *(const bh8*)(gq + j * 8);
    bh8 vk = *(const bh8*)(gk + j * 8);
    int ci = (part * 64 + j * 8) ^ sw;
    *(bh8*)&lsQ[row * 128 + ci] = vq;
    *(bh8*)&lsKV[row * 128 + ci] = vk;
  }
  if (tid < 128) lsS[tid] = s[(nb * 16 + h) * 128 + tid];
  __syncthreads();

  if (tid < 128) {
    int rr = tid, swr = (rr & 7) << 3;
    float dsum = 0.f;
    for (int dd = 0; dd < 128; dd++) {
      int d = (dd + rr) & 127;
      dsum += bf2f(lsQ[rr * 128 + (d ^ swr)]) * lsS[d];
    }
    lsDen[rr] = dsum;
  }
  __syncthreads();

  int wr = wid >> 1, wc = wid & 1;
  int r = lane & 15, ko = (lane >> 4) * 8;
  fx4 acc[4][4] = {};
#pragma unroll
  for (int ks = 0; ks < 4; ks++) {
    bh8 af[4], bfr[4];
#pragma unroll
    for (int mi = 0; mi < 4; mi++) {
      int rw = wr * 64 + mi * 16 + r;
      af[mi] = *(const bh8*)&lsQ[rw * 128 + ((ks * 32 + ko) ^ ((rw & 7) << 3))];
    }
#pragma unroll
    for (int ni = 0; ni < 4; ni++) {
      int rw = wc * 64 + ni * 16 + r;
      bfr[ni] = *(const bh8*)&lsKV[rw * 128 + ((ks * 32 + ko) ^ ((rw & 7) << 3))];
    }
#pragma unroll
    for (int mi = 0; mi < 4; mi++)
#pragma unroll
      for (int ni = 0; ni < 4; ni++)
        acc[mi][ni] = __builtin_amdgcn_mfma_f32_16x16x32_bf16(af[mi], bfr[ni],
                                                              acc[mi][ni], 0, 0, 0);
  }
#pragma unroll
  for (int mi = 0; mi < 4; mi++)
#pragma unroll
    for (int ni = 0; ni < 4; ni++)
#pragma unroll
      for (int j = 0; j < 4; j++) {
        int li = wr * 64 + mi * 16 + (lane >> 4) * 4 + j;
        int e = wc * 64 + ni * 16 + (lane & 15);
        int l = l0 + li;
        float v = qmask[nb * 4096 + l] ? 0.f : acc[mi][ni][j] / lsDen[li];
        out[((size_t)(nb * 4096 + l)) * 2048 + h * 128 + e] = v;
      }
}

// ---------------- launch ----------------
extern "C" void kernel_launch(void* const* d_in, const int* in_sizes, int n_in,
                              void* d_out, int out_size, void* d_ws, size_t ws_size,
                              hipStream_t stream) {
  const float* query = (const float*)d_in[0];
  const float* key   = (const float*)d_in[1];
  const float* Wq    = (const float*)d_in[2];
  const float* Wk    = (const float*)d_in[3];
  const float* Wv    = (const float*)d_in[4];
  const int* qmask   = (const int*)d_in[5];
  const int* kmask   = (const int*)d_in[6];
  float* out = (float*)d_out;
  char* ws = (char*)d_ws;

  u16* qb   = (u16*)(ws + 0);
  u16* kb   = (u16*)(ws + 67108864ull);
  u16* Wqb  = (u16*)(ws + 134217728ull);
  u16* Wkb  = (u16*)(ws + 142606336ull);
  u16* Wvb  = (u16*)(ws + 150994944ull);
  u16* pq   = (u16*)(ws + 159383552ull);
  u16* kvT  = (u16*)(ws + 226492416ull);
  float* sb = (float*)(ws + 228589568ull);
  // pk and v die before k_att -> live in d_out
  u16* pk = (u16*)d_out;
  u16* vb = (u16*)d_out + 33554432ull;

  k_cvt<<<2048, 256, 0, stream>>>(query, qb, 33554432 / 4);
  k_cvt<<<2048, 256, 0, stream>>>(key, kb, 33554432 / 4);
  k_cvt<<<512, 256, 0, stream>>>(Wq, Wqb, 4194304 / 4);
  k_cvt<<<512, 256, 0, stream>>>(Wk, Wkb, 4194304 / 4);
  k_cvt<<<512, 256, 0, stream>>>(Wv, Wvb, 4194304 / 4);

  k_gemm256<1><<<512, 512, 131072, stream>>>(qb, Wqb, pq, nullptr);
  k_gemm256<2><<<512, 512, 131072, stream>>>(kb, Wkb, pk, kmask);
  k_gemm256<0><<<512, 512, 131072, stream>>>(kb, Wvb, vb, nullptr);

  k_ssum<<<64, 512, 0, stream>>>(pk, sb);
  k_kv<<<64, 256, 0, stream>>>(pk, vb, kvT);
  k_att<<<2048, 256, 0, stream>>>(pq, kvT, sb, qmask, out);
}

// Round 5
// 820.161 us; speedup vs baseline: 2.7650x; 1.1226x over previous
//
#include <hip/hip_runtime.h>
#include <stdint.h>

typedef __attribute__((ext_vector_type(8))) short    bh8;   // 8 x bf16 (4 VGPR)
typedef __attribute__((ext_vector_type(4))) float    fx4;
typedef __attribute__((ext_vector_type(16))) float   f16v;  // 32x32 MFMA acc
typedef __attribute__((ext_vector_type(4))) float    f4v;
typedef unsigned short u16;
typedef __attribute__((ext_vector_type(4))) unsigned short u16x4;

#define DEV static __device__ __forceinline__

DEV u16 f2bf(float f) {                       // RNE fp32 -> bf16
  unsigned u = __float_as_uint(f);
  u += 0x7FFFu + ((u >> 16) & 1u);
  return (u16)(u >> 16);
}
DEV float bf2f(u16 s) { return __uint_as_float(((unsigned)s) << 16); }
DEV float softplus_f(float x) { return fmaxf(x, 0.f) + log1pf(expf(-fabsf(x))); }

DEV void gload_lds16(const u16* g, u16* l) {  // 16B/lane async global->LDS
  __builtin_amdgcn_global_load_lds(
      (const __attribute__((address_space(1))) unsigned int*)g,
      (__attribute__((address_space(3))) unsigned int*)l, 16, 0, 0);
}
DEV void stage2(const u16* s, u16* d) {       // one 128-row piece of a half-tile
  gload_lds16(s, d);
  gload_lds16(s + 131072, d + 4096);          // +64 rows (ld = 2048)
}

// ---------------- fp32 -> bf16 convert (vectorized) ----------------
__global__ __launch_bounds__(256) void k_cvt(const float* __restrict__ in,
                                             u16* __restrict__ out, int n4) {
  int i = blockIdx.x * 256 + threadIdx.x;
  int stride = gridDim.x * 256;
  for (; i < n4; i += stride) {
    f4v v = ((const f4v*)in)[i];
    u16x4 o;
    o.x = f2bf(v.x); o.y = f2bf(v.y); o.z = f2bf(v.z); o.w = f2bf(v.w);
    ((u16x4*)out)[i] = o;
  }
}

// ============ 256x256 8-phase GEMM, 32x32x16 MFMA (T2+T3+T4+T5) ============
// C[i,j] = sum_k A[i,k]*B[j,k]; M=16384, N=2048, K=2048 hardcoded.
// LDS (u16 idx): buf0.A h0=0 h1=8192 | buf0.B h0=16384 h1=24576
//                buf1.A h0=32768 h1=40960 | buf1.B h0=49152 h1=57344
// Tiles 256r x 64c row-major; ds_read XOR-swizzle idx ^= (row&7)<<3;
// staging = linear LDS dest + inverse-swizzled global source (rule #21).
// Per wave: 128x64 output = 4x2 frags of 32x32, acc in 8 named f32x16 (rule #20).
// Phase reads: {16, 0, 8, 0} b128 per K-tile; 8 MFMA(32x32x16) per phase.

#define MM32(a, b, c) __builtin_amdgcn_mfma_f32_32x32x16_bf16(a, b, c, 0, 0, 0)
#define LD32(BASE, RR, KS) \
  (*(const bh8*)&lsg[(BASE) + (RR) * 64 + ((((KS) * 16) + kg) ^ swz)])

#define LDA(AB, RO)                                                           \
  a0_0 = LD32(AB, arow + (RO),      0); a0_1 = LD32(AB, arow + (RO),      1); \
  a0_2 = LD32(AB, arow + (RO),      2); a0_3 = LD32(AB, arow + (RO),      3); \
  a1_0 = LD32(AB, arow + (RO) + 32, 0); a1_1 = LD32(AB, arow + (RO) + 32, 1); \
  a1_2 = LD32(AB, arow + (RO) + 32, 2); a1_3 = LD32(AB, arow + (RO) + 32, 3);

#define LDB(BP, BB, RO)                                                       \
  BP##_0 = LD32(BB, brow + (RO), 0); BP##_1 = LD32(BB, brow + (RO), 1);       \
  BP##_2 = LD32(BB, brow + (RO), 2); BP##_3 = LD32(BB, brow + (RO), 3);

#define CL(BP, C0, C1)                                        \
  C0 = MM32(a0_0, BP##_0, C0); C1 = MM32(a1_0, BP##_0, C1);   \
  C0 = MM32(a0_1, BP##_1, C0); C1 = MM32(a1_1, BP##_1, C1);   \
  C0 = MM32(a0_2, BP##_2, C0); C1 = MM32(a1_2, BP##_2, C1);   \
  C0 = MM32(a0_3, BP##_3, C0); C1 = MM32(a1_3, BP##_3, C1);

#define WVA asm volatile("s_waitcnt vmcnt(4)")

#define PH(CLUSTER, WAITS, SSRC, SDST, ...) {   \
  __VA_ARGS__                                   \
  stage2(SSRC, SDST);                           \
  __builtin_amdgcn_s_barrier();                 \
  asm volatile("s_waitcnt lgkmcnt(0)");         \
  __builtin_amdgcn_s_setprio(1);                \
  CLUSTER                                       \
  __builtin_amdgcn_s_setprio(0);                \
  WAITS;                                        \
  __builtin_amdgcn_s_barrier();                 \
}

// epilogue: D col=lane&31, row=(r&3)+8*(r>>2)+4*(lane>>5)  (m74/m101)
#define STX(AC, R, GIB, GJ) {                                  \
  float vv = AC[R];                                            \
  if (EPI >= 1) vv = softplus_f(vv);                           \
  int gi = (GIB) + ((R) & 3) + 8 * ((R) >> 2);                 \
  if (EPI == 2) { if (mask[gi]) vv = 0.f; }                    \
  C[(size_t)gi * 2048 + (GJ)] = f2bf(vv);                      \
}
#define ST16(AC, MI, NI) {                                     \
  int gib = bm0 + wr * 128 + (MI) * 32 + h4;                   \
  int gj  = bn0 + wc * 64 + (NI) * 32 + l31;                   \
  STX(AC, 0, gib, gj)  STX(AC, 1, gib, gj)  STX(AC, 2, gib, gj)  STX(AC, 3, gib, gj)  \
  STX(AC, 4, gib, gj)  STX(AC, 5, gib, gj)  STX(AC, 6, gib, gj)  STX(AC, 7, gib, gj)  \
  STX(AC, 8, gib, gj)  STX(AC, 9, gib, gj)  STX(AC, 10, gib, gj) STX(AC, 11, gib, gj) \
  STX(AC, 12, gib, gj) STX(AC, 13, gib, gj) STX(AC, 14, gib, gj) STX(AC, 15, gib, gj) \
}

template <int EPI>   // 0 plain, 1 softplus, 2 softplus + row-mask zero
__global__ __launch_bounds__(512, 2) void k_gemm256(
    const u16* __restrict__ A, const u16* __restrict__ B, u16* __restrict__ C,
    const int* __restrict__ mask) {
  extern __shared__ u16 lsg[];                 // 128 KiB dynamic
  int tid = threadIdx.x, lane = tid & 63, wid = tid >> 6;
  int bm0 = (blockIdx.x >> 3) << 8;            // 64 M-tiles
  int bn0 = (blockIdx.x & 7) << 8;             // 8 N-tiles (bid%8 -> XCD locality)
  int wr = wid >> 2, wc = wid & 3;
  int l31 = lane & 31;
  int kg = (lane >> 5) * 8;                    // k-granule within 64-col tile
  int h4 = (lane >> 5) * 4;
  int swz = (lane & 7) << 3;
  int abase0 = wr * 8192;                      // this wave's A half (buf0)
  int abase1 = 32768 + wr * 8192;              // (buf1)
  int bbase0 = 16384 + (wc >> 1) * 8192;       // this wave's B half (buf0)
  int bbase1 = 49152 + (wc >> 1) * 8192;       // (buf1)
  int arow = l31;                              // row within A half (+mi*32)
  int brow = (wc & 1) * 64 + l31;              // row within B half (+ni*32)
  int lr = lane >> 3, cg = (lane & 7) ^ lr;    // inverse-swizzled source granule
  const u16* srcA = A + (size_t)(bm0 + wid * 8 + lr) * 2048 + cg * 8;
  const u16* srcB = B + (size_t)(bn0 + wid * 8 + lr) * 2048 + cg * 8;
  u16* lsu = lsg + wid * 512;                  // wave-uniform stage dest base

  f16v acc00 = {}, acc01 = {}, acc10 = {}, acc11 = {},
       acc20 = {}, acc21 = {}, acc30 = {}, acc31 = {};
  bh8 a0_0 = {}, a0_1 = {}, a0_2 = {}, a0_3 = {},
      a1_0 = {}, a1_1 = {}, a1_2 = {}, a1_3 = {};
  bh8 b0_0 = {}, b0_1 = {}, b0_2 = {}, b0_3 = {},
      b1_0 = {}, b1_1 = {}, b1_2 = {}, b1_3 = {};

  // prologue: tile0 all 4 halves + tile1 A-h0,B-h0; vmcnt(4) -> buf0 resident
  stage2(srcA, lsu + 0);                       // buf0.A h0  (t0)
  stage2(srcB, lsu + 16384);                   // buf0.B h0
  stage2(srcA + 262144, lsu + 8192);           // buf0.A h1
  stage2(srcB + 262144, lsu + 24576);          // buf0.B h1
  stage2(srcA + 64, lsu + 32768);              // buf1.A h0  (t1)
  stage2(srcB + 64, lsu + 49152);              // buf1.B h0
  asm volatile("s_waitcnt vmcnt(4)");
  __builtin_amdgcn_s_barrier();

  for (int it = 0; it < 16; it++) {
    int t1 = 2 * it + 1;
    int t2 = (2 * it + 2) & 31;                // wrapped prefetch (dup, unread)
    int t3 = (2 * it + 3) & 31;
    // phases 1-4: tile 2it from buf0
    PH(CL(b0, acc00, acc10), (void)0, srcA + 262144 + t1 * 64, lsu + 40960,
       LDA(abase0, 0) LDB(b0, bbase0, 0) LDB(b1, bbase0, 32))   // buf1.A h1 (t1)
    PH(CL(b1, acc01, acc11), (void)0, srcB + 262144 + t1 * 64, lsu + 57344, ) // buf1.B h1
    PH(CL(b1, acc21, acc31), (void)0, srcB + t2 * 64, lsu + 16384,
       LDA(abase0, 64))                                         // buf0.B h0 (t2)
    PH(CL(b0, acc20, acc30), WVA, srcA + t2 * 64, lsu + 0, )    // buf0.A h0 (t2)
    // phases 5-8: tile 2it+1 from buf1
    PH(CL(b0, acc00, acc10), (void)0, srcA + 262144 + t2 * 64, lsu + 8192,
       LDA(abase1, 0) LDB(b0, bbase1, 0) LDB(b1, bbase1, 32))   // buf0.A h1 (t2)
    PH(CL(b1, acc01, acc11), (void)0, srcB + 262144 + t2 * 64, lsu + 24576, ) // buf0.B h1
    PH(CL(b1, acc21, acc31), (void)0, srcB + t3 * 64, lsu + 49152,
       LDA(abase1, 64))                                         // buf1.B h0 (t3)
    PH(CL(b0, acc20, acc30), WVA, srcA + t3 * 64, lsu + 32768, ) // buf1.A h0 (t3)
  }

  ST16(acc00, 0, 0) ST16(acc01, 0, 1)
  ST16(acc10, 1, 0) ST16(acc11, 1, 1)
  ST16(acc20, 2, 0) ST16(acc21, 2, 1)
  ST16(acc30, 3, 0) ST16(acc31, 3, 1)
}

// ------- split-K kv: part[bid][e*128+d] = sum_{k in slab} pk[k,d]*v[k,e] ----
// also computes s-partials (column sums of pk over the slab) from registers.
__global__ __launch_bounds__(256, 2) void k_kv2(const u16* __restrict__ pk,
                                                const u16* __restrict__ v,
                                                float* __restrict__ part,
                                                float* __restrict__ spart) {
  int nh = blockIdx.x >> 3, slab = blockIdx.x & 7;
  int n = nh >> 4, h = nh & 15;
  __shared__ u16 lsA[128 * 32];   // pk^T tile: [d][k]
  __shared__ u16 lsB[128 * 32];   // v^T tile:  [e][k]
  __shared__ float redS[32][128];
  int tid = threadIdx.x, lane = tid & 63, wid = tid >> 6;
  int wr = wid >> 1, wc = wid & 1;
  int kk = tid >> 3;              // 0..31 (k within 32-k slab)
  int dg = (tid & 7) * 16;        // 0..112 (16 cols per thread)
  size_t rowbase = ((size_t)(n * 4096 + slab * 512) + kk) * 2048 + h * 128 + dg;
  int r = lane & 15, ko = (lane >> 4) * 8;
  fx4 acc[4][4] = {};
  float sA[16];
#pragma unroll
  for (int i = 0; i < 16; i++) sA[i] = 0.f;
  for (int k0 = 0; k0 < 512; k0 += 32) {
    __syncthreads();
    bh8 a0 = *(const bh8*)(pk + rowbase + (size_t)k0 * 2048);
    bh8 a1 = *(const bh8*)(pk + rowbase + (size_t)k0 * 2048 + 8);
    bh8 b0 = *(const bh8*)(v + rowbase + (size_t)k0 * 2048);
    bh8 b1 = *(const bh8*)(v + rowbase + (size_t)k0 * 2048 + 8);
#pragma unroll
    for (int i = 0; i < 8; i++) {
      sA[i] += bf2f((u16)a0[i]);
      sA[8 + i] += bf2f((u16)a1[i]);
    }
#pragma unroll
    for (int i = 0; i < 8; i++) {
      lsA[(dg + i) * 32 + kk] = (u16)a0[i];
      lsA[(dg + 8 + i) * 32 + kk] = (u16)a1[i];
      lsB[(dg + i) * 32 + kk] = (u16)b0[i];
      lsB[(dg + 8 + i) * 32 + kk] = (u16)b1[i];
    }
    __syncthreads();
    bh8 af[4], bfr[4];
#pragma unroll
    for (int mi = 0; mi < 4; mi++)
      af[mi] = *(const bh8*)&lsA[(wr * 64 + mi * 16 + r) * 32 + ko];
#pragma unroll
    for (int ni = 0; ni < 4; ni++)
      bfr[ni] = *(const bh8*)&lsB[(wc * 64 + ni * 16 + r) * 32 + ko];
#pragma unroll
    for (int mi = 0; mi < 4; mi++)
#pragma unroll
      for (int ni = 0; ni < 4; ni++)
        acc[mi][ni] = __builtin_amdgcn_mfma_f32_16x16x32_bf16(af[mi], bfr[ni],
                                                              acc[mi][ni], 0, 0, 0);
  }
  // D rows = d, cols = e; store f32 partial at [e][d]
#pragma unroll
  for (int mi = 0; mi < 4; mi++)
#pragma unroll
    for (int ni = 0; ni < 4; ni++)
#pragma unroll
      for (int j = 0; j < 4; j++) {
        int d = wr * 64 + mi * 16 + (lane >> 4) * 4 + j;
        int e = wc * 64 + ni * 16 + (lane & 15);
        part[(size_t)blockIdx.x * 16384 + e * 128 + d] = acc[mi][ni][j];
      }
  // s partial reduce over kk
#pragma unroll
  for (int i = 0; i < 16; i++) redS[kk][dg + i] = sA[i];
  __syncthreads();
  if (tid < 128) {
    float s = 0.f;
#pragma unroll
    for (int p = 0; p < 32; p++) s += redS[p][tid];
    spart[blockIdx.x * 128 + tid] = s;
  }
}

// ------- reduce split-K partials -> kvT (bf16) and s (f32) -------
__global__ __launch_bounds__(256) void k_red(const float* __restrict__ part,
                                             const float* __restrict__ spart,
                                             u16* __restrict__ kvT,
                                             float* __restrict__ sb) {
  int nh = blockIdx.x, tid = threadIdx.x;
  for (int i = tid; i < 16384; i += 256) {
    float s = 0.f;
#pragma unroll
    for (int sl = 0; sl < 8; sl++) s += part[(size_t)(nh * 8 + sl) * 16384 + i];
    kvT[(size_t)nh * 16384 + i] = f2bf(s);
  }
  if (tid < 128) {
    float s = 0.f;
#pragma unroll
    for (int sl = 0; sl < 8; sl++) s += spart[(nh * 8 + sl) * 128 + tid];
    sb[nh * 128 + tid] = s;
  }
}

// ---------------- final: out = (pq @ kv) / (pq @ s), query-masked ----------
__global__ __launch_bounds__(256, 2) void k_att(
    const u16* __restrict__ pq, const u16* __restrict__ kvT,
    const float* __restrict__ s, const int* __restrict__ qmask,
    float* __restrict__ out) {
  int b = blockIdx.x;
  int lt = b & 31, h = (b >> 5) & 15, nb = b >> 9;
  int l0 = lt * 128;
  __shared__ u16 lsQ[128 * 128];
  __shared__ u16 lsKV[128 * 128];
  __shared__ float lsS[128];
  __shared__ float lsDen[128];
  int tid = threadIdx.x, lane = tid & 63, wid = tid >> 6;

  int row = tid >> 1, part = tid & 1;
  const u16* gq = pq + ((size_t)(nb * 4096 + l0 + row)) * 2048 + h * 128 + part * 64;
  const u16* gk = kvT + ((size_t)(nb * 16 + h) * 128 + row) * 128 + part * 64;
  int sw = (row & 7) << 3;
#pragma unroll
  for (int j = 0; j < 8; j++) {
    bh8 vq = *(const bh8*)(gq + j * 8);
    bh8 vk = *(const bh8*)(gk + j * 8);
    int ci = (part * 64 + j * 8) ^ sw;
    *(bh8*)&lsQ[row * 128 + ci] = vq;
    *(bh8*)&lsKV[row * 128 + ci] = vk;
  }
  if (tid < 128) lsS[tid] = s[(nb * 16 + h) * 128 + tid];
  __syncthreads();

  if (tid < 128) {
    int rr = tid, swr = (rr & 7) << 3;
    float dsum = 0.f;
    for (int dd = 0; dd < 128; dd++) {
      int d = (dd + rr) & 127;
      dsum += bf2f(lsQ[rr * 128 + (d ^ swr)]) * lsS[d];
    }
    lsDen[rr] = dsum;
  }
  __syncthreads();

  int wr = wid >> 1, wc = wid & 1;
  int r = lane & 15, ko = (lane >> 4) * 8;
  fx4 acc[4][4] = {};
#pragma unroll
  for (int ks = 0; ks < 4; ks++) {
    bh8 af[4], bfr[4];
#pragma unroll
    for (int mi = 0; mi < 4; mi++) {
      int rw = wr * 64 + mi * 16 + r;
      af[mi] = *(const bh8*)&lsQ[rw * 128 + ((ks * 32 + ko) ^ ((rw & 7) << 3))];
    }
#pragma unroll
    for (int ni = 0; ni < 4; ni++) {
      int rw = wc * 64 + ni * 16 + r;
      bfr[ni] = *(const bh8*)&lsKV[rw * 128 + ((ks * 32 + ko) ^ ((rw & 7) << 3))];
    }
#pragma unroll
    for (int mi = 0; mi < 4; mi++)
#pragma unroll
      for (int ni = 0; ni < 4; ni++)
        acc[mi][ni] = __builtin_amdgcn_mfma_f32_16x16x32_bf16(af[mi], bfr[ni],
                                                              acc[mi][ni], 0, 0, 0);
  }
#pragma unroll
  for (int mi = 0; mi < 4; mi++)
#pragma unroll
    for (int ni = 0; ni < 4; ni++)
#pragma unroll
      for (int j = 0; j < 4; j++) {
        int li = wr * 64 + mi * 16 + (lane >> 4) * 4 + j;
        int e = wc * 64 + ni * 16 + (lane & 15);
        int l = l0 + li;
        float v = qmask[nb * 4096 + l] ? 0.f : acc[mi][ni][j] / lsDen[li];
        out[((size_t)(nb * 4096 + l)) * 2048 + h * 128 + e] = v;
      }
}

// ---------------- launch ----------------
extern "C" void kernel_launch(void* const* d_in, const int* in_sizes, int n_in,
                              void* d_out, int out_size, void* d_ws, size_t ws_size,
                              hipStream_t stream) {
  const float* query = (const float*)d_in[0];
  const float* key   = (const float*)d_in[1];
  const float* Wq    = (const float*)d_in[2];
  const float* Wk    = (const float*)d_in[3];
  const float* Wv    = (const float*)d_in[4];
  const int* qmask   = (const int*)d_in[5];
  const int* kmask   = (const int*)d_in[6];
  float* out = (float*)d_out;
  char* ws = (char*)d_ws;

  u16* qb   = (u16*)(ws + 0);
  u16* kb   = (u16*)(ws + 67108864ull);
  u16* Wqb  = (u16*)(ws + 134217728ull);
  u16* Wkb  = (u16*)(ws + 142606336ull);
  u16* Wvb  = (u16*)(ws + 150994944ull);
  u16* pq   = (u16*)(ws + 159383552ull);
  u16* kvT  = (u16*)(ws + 226492416ull);
  float* sb = (float*)(ws + 228589568ull);
  // split-K partials live in qb's region (dead after the first GEMM)
  float* kvpart = (float*)(ws + 0);            // 512 * 16384 * 4 = 33.5 MB
  float* spart  = (float*)(ws + 33554432ull);  // 512 * 128 * 4 = 256 KB
  // pk and v die before k_att -> live in d_out
  u16* pk = (u16*)d_out;
  u16* vb = (u16*)d_out + 33554432ull;

  k_cvt<<<2048, 256, 0, stream>>>(query, qb, 33554432 / 4);
  k_cvt<<<2048, 256, 0, stream>>>(key, kb, 33554432 / 4);
  k_cvt<<<512, 256, 0, stream>>>(Wq, Wqb, 4194304 / 4);
  k_cvt<<<512, 256, 0, stream>>>(Wk, Wkb, 4194304 / 4);
  k_cvt<<<512, 256, 0, stream>>>(Wv, Wvb, 4194304 / 4);

  k_gemm256<1><<<512, 512, 131072, stream>>>(qb, Wqb, pq, nullptr);
  k_gemm256<2><<<512, 512, 131072, stream>>>(kb, Wkb, pk, kmask);
  k_gemm256<0><<<512, 512, 131072, stream>>>(kb, Wvb, vb, nullptr);

  k_kv2<<<512, 256, 0, stream>>>(pk, vb, kvpart, spart);
  k_red<<<64, 256, 0, stream>>>(kvpart, spart, kvT, sb);
  k_att<<<2048, 256, 0, stream>>>(pq, kvT, sb, qmask, out);
}

// Round 7
// 744.958 us; speedup vs baseline: 3.0441x; 1.1010x over previous
//
#include <hip/hip_runtime.h>
#include <stdint.h>

typedef __attribute__((ext_vector_type(8))) short    bh8;   // 8 x bf16 (4 VGPR)
typedef __attribute__((ext_vector_type(4))) float    fx4;   // MFMA acc
typedef __attribute__((ext_vector_type(4))) float    f4v;
typedef unsigned short u16;
typedef __attribute__((ext_vector_type(4))) unsigned short u16x4;

#define DEV static __device__ __forceinline__

DEV u16 f2bf(float f) {                       // RNE fp32 -> bf16
  unsigned u = __float_as_uint(f);
  u += 0x7FFFu + ((u >> 16) & 1u);
  return (u16)(u >> 16);
}
DEV float bf2f(u16 s) { return __uint_as_float(((unsigned)s) << 16); }
DEV float softplus_f(float x) { return fmaxf(x, 0.f) + log1pf(expf(-fabsf(x))); }

DEV void gload_lds16(const u16* g, u16* l) {  // 16B/lane async global->LDS
  __builtin_amdgcn_global_load_lds(
      (const __attribute__((address_space(1))) unsigned int*)g,
      (__attribute__((address_space(3))) unsigned int*)l, 16, 0, 0);
}
DEV void stage2(const u16* s, u16* d) {       // one 128-row piece of a half-tile
  gload_lds16(s, d);
  gload_lds16(s + 131072, d + 4096);          // +64 rows (ld = 2048)
}

// ---------------- fp32 -> bf16 convert (vectorized) ----------------
__global__ __launch_bounds__(256) void k_cvt(const float* __restrict__ in,
                                             u16* __restrict__ out, int n4) {
  int i = blockIdx.x * 256 + threadIdx.x;
  int stride = gridDim.x * 256;
  for (; i < n4; i += stride) {
    f4v v = ((const f4v*)in)[i];
    u16x4 o;
    o.x = f2bf(v.x); o.y = f2bf(v.y); o.z = f2bf(v.z); o.w = f2bf(v.w);
    ((u16x4*)out)[i] = o;
  }
}

// ================= 256x256 8-phase GEMM (T2+T3+T4+T5) =================
// C[i,j] = sum_k A[i,k]*B[j,k]; M=16384, N=2048, K=2048 hardcoded.
// LDS (u16 idx): buf0.A h0=0 h1=8192 | buf0.B h0=16384 h1=24576
//                buf1.A h0=32768 h1=40960 | buf1.B h0=49152 h1=57344
// Tiles 256r x 64c row-major; ds_read XOR-swizzle idx ^= (row&7)<<3;
// staging = linear LDS dest + inverse-swizzled global source (rule #21).
// XCD-aware 2D chunked mapping: XCD=bid%8 owns A-panels [8x,8x+8) exclusively
// -> staging served from L2 instead of streaming all of A through each XCD.
// Fragment-dedup phases: per K-tile reads {16, 0, 8, 0} b128/wave.

#define MM(a, b, c) __builtin_amdgcn_mfma_f32_16x16x32_bf16(a, b, c, 0, 0, 0)
#define LD(BASE, RR, KS) \
  (*(const bh8*)&lsg[(BASE) + (RR) * 64 + ((((KS) * 32) + ko8) ^ swz)])

#define DECLQ(Q)                                                          \
  fx4 acc##Q##00 = {}, acc##Q##01 = {}, acc##Q##10 = {}, acc##Q##11 = {}, \
      acc##Q##20 = {}, acc##Q##21 = {}, acc##Q##30 = {}, acc##Q##31 = {}

#define WL asm volatile("s_waitcnt lgkmcnt(0)")
#define WV asm volatile("s_waitcnt vmcnt(4)"); asm volatile("s_waitcnt lgkmcnt(0)")

#define LDA8(AB)                                                \
  a_00 = LD(AB, arow0,      0); a_01 = LD(AB, arow0,      1);   \
  a_10 = LD(AB, arow0 + 16, 0); a_11 = LD(AB, arow0 + 16, 1);   \
  a_20 = LD(AB, arow0 + 32, 0); a_21 = LD(AB, arow0 + 32, 1);   \
  a_30 = LD(AB, arow0 + 48, 0); a_31 = LD(AB, arow0 + 48, 1);

#define LDB4(BN, BB)                                                        \
  b##BN##_00 = LD(BB, brow0,      0); b##BN##_01 = LD(BB, brow0,      1);   \
  b##BN##_10 = LD(BB, brow0 + 16, 0); b##BN##_11 = LD(BB, brow0 + 16, 1);

#define MFMA16(Q, BN)                                                           \
  acc##Q##00 = MM(a_00, b##BN##_00, acc##Q##00);                                \
  acc##Q##01 = MM(a_00, b##BN##_10, acc##Q##01);                                \
  acc##Q##10 = MM(a_10, b##BN##_00, acc##Q##10);                                \
  acc##Q##11 = MM(a_10, b##BN##_10, acc##Q##11);                                \
  acc##Q##20 = MM(a_20, b##BN##_00, acc##Q##20);                                \
  acc##Q##21 = MM(a_20, b##BN##_10, acc##Q##21);                                \
  acc##Q##30 = MM(a_30, b##BN##_00, acc##Q##30);                                \
  acc##Q##31 = MM(a_30, b##BN##_10, acc##Q##31);                                \
  acc##Q##00 = MM(a_01, b##BN##_01, acc##Q##00);                                \
  acc##Q##01 = MM(a_01, b##BN##_11, acc##Q##01);                                \
  acc##Q##10 = MM(a_11, b##BN##_01, acc##Q##10);                                \
  acc##Q##11 = MM(a_11, b##BN##_11, acc##Q##11);                                \
  acc##Q##20 = MM(a_21, b##BN##_01, acc##Q##20);                                \
  acc##Q##21 = MM(a_21, b##BN##_11, acc##Q##21);                                \
  acc##Q##30 = MM(a_31, b##BN##_01, acc##Q##30);                                \
  acc##Q##31 = MM(a_31, b##BN##_11, acc##Q##31);

// LOADS go in __VA_ARGS__ (may be empty)
#define PHASE(Q, BN, WAITS, SSRC, SDST, ...) {  \
  __VA_ARGS__                                   \
  stage2(SSRC, SDST);                           \
  __builtin_amdgcn_s_barrier();                 \
  __builtin_amdgcn_s_setprio(1);                \
  MFMA16(Q, BN)                                 \
  __builtin_amdgcn_s_setprio(0);                \
  WAITS;                                        \
  __builtin_amdgcn_s_barrier();                 \
}

// store one 16x16 fragment (4 rows x-w), with epilogue EPI
#define STE(AC, EL, JOFF) {                                                   \
  float v = AC.EL;                                                            \
  if (EPI >= 1) v = softplus_f(v);                                            \
  if (EPI == 2) { if (mask[gi0 + JOFF]) v = 0.f; }                            \
  C[(size_t)(gi0 + JOFF) * 2048 + gj] = f2bf(v);                              \
}
#define ST1(AC, QR, QC, MI, NI) {                                             \
  int gi0 = bm0 + (QR) * 128 + wr * 64 + (MI) * 16 + (lane >> 4) * 4;         \
  int gj  = bn0 + (QC) * 128 + wc * 32 + (NI) * 16 + l15;                     \
  STE(AC, x, 0) STE(AC, y, 1) STE(AC, z, 2) STE(AC, w, 3)                     \
}
#define EPIQ(Q, QR, QC)                                                       \
  ST1(acc##Q##00, QR, QC, 0, 0) ST1(acc##Q##01, QR, QC, 0, 1)                 \
  ST1(acc##Q##10, QR, QC, 1, 0) ST1(acc##Q##11, QR, QC, 1, 1)                 \
  ST1(acc##Q##20, QR, QC, 2, 0) ST1(acc##Q##21, QR, QC, 2, 1)                 \
  ST1(acc##Q##30, QR, QC, 3, 0) ST1(acc##Q##31, QR, QC, 3, 1)

template <int EPI>   // 0 plain, 1 softplus, 2 softplus + row-mask zero
__global__ __launch_bounds__(512, 2) void k_gemm256(
    const u16* __restrict__ A, const u16* __restrict__ B, u16* __restrict__ C,
    const int* __restrict__ mask) {
  extern __shared__ u16 lsg[];                 // 128 KiB dynamic
  int tid = threadIdx.x, lane = tid & 63, wid = tid >> 6;
  // XCD-aware 2D chunk: XCD x = bid%8 owns m-tiles [8x, 8x+8), n = i>>3.
  int xcd = blockIdx.x & 7, i = blockIdx.x >> 3;
  int bm0 = (xcd * 8 + (i & 7)) << 8;          // 64 M-tiles, XCD-exclusive
  int bn0 = (i >> 3) << 8;                     // 8 N-tiles
  int wr = wid >> 2, wc = wid & 3;
  int l15 = lane & 15, ko8 = (lane >> 4) * 8;
  int swz = (l15 & 7) << 3;
  int arow0 = wr * 64 + l15, brow0 = wc * 32 + l15;
  int lr = lane >> 3, cg = (lane & 7) ^ lr;    // inverse-swizzled source granule
  const u16* srcA = A + (size_t)(bm0 + wid * 8 + lr) * 2048 + cg * 8;
  const u16* srcB = B + (size_t)(bn0 + wid * 8 + lr) * 2048 + cg * 8;
  u16* lsu = lsg + wid * 512;                  // wave-uniform stage dest base

  DECLQ(0); DECLQ(1); DECLQ(2); DECLQ(3);
  bh8 a_00 = {}, a_01 = {}, a_10 = {}, a_11 = {},
      a_20 = {}, a_21 = {}, a_30 = {}, a_31 = {};
  bh8 b0_00 = {}, b0_01 = {}, b0_10 = {}, b0_11 = {};
  bh8 b1_00 = {}, b1_01 = {}, b1_10 = {}, b1_11 = {};

  // prologue: tile0 all 4 halves + tile1 A-h0,B-h0; vmcnt(4) -> buf0 resident
  stage2(srcA, lsu + 0);                       // buf0.A h0  (t0)
  stage2(srcB, lsu + 16384);                   // buf0.B h0
  stage2(srcA + 262144, lsu + 8192);           // buf0.A h1
  stage2(srcB + 262144, lsu + 24576);          // buf0.B h1
  stage2(srcA + 64, lsu + 32768);              // buf1.A h0  (t1)
  stage2(srcB + 64, lsu + 49152);              // buf1.B h0
  asm volatile("s_waitcnt vmcnt(4)");
  __builtin_amdgcn_s_barrier();

  for (int it = 0; it < 16; it++) {
    int t1 = 2 * it + 1;
    int t2 = (2 * it + 2) & 31;                // wrapped prefetch (dup, unread)
    int t3 = (2 * it + 3) & 31;
    // phases 1-4: tile 2it from buf0.  Quadrant key: 0=(A0,B0) 1=(A0,B1)
    // 3=(A1,B1) 2=(A1,B0).  Reads per phase: {16, 0, 8, 0}.
    PHASE(0, 0, WL, srcA + 262144 + t1 * 64, lsu + 40960,
          LDA8(0) LDB4(0, 16384) LDB4(1, 24576))       // stage buf1.A h1 (t1)
    PHASE(1, 1, WL, srcB + 262144 + t1 * 64, lsu + 57344, )  // buf1.B h1 (t1)
    PHASE(3, 1, WL, srcA + t2 * 64, lsu + 0,
          LDA8(8192))                                   // buf0.A h0 (t2)
    PHASE(2, 0, WV, srcB + t2 * 64, lsu + 16384, )      // buf0.B h0 (t2)
    // phases 5-8: tile 2it+1 from buf1
    PHASE(0, 0, WL, srcA + 262144 + t2 * 64, lsu + 8192,
          LDA8(32768) LDB4(0, 49152) LDB4(1, 57344))    // buf0.A h1 (t2)
    PHASE(1, 1, WL, srcB + 262144 + t2 * 64, lsu + 24576, ) // buf0.B h1 (t2)
    PHASE(3, 1, WL, srcA + t3 * 64, lsu + 32768,
          LDA8(40960))                                  // buf1.B h0 (t3)
    PHASE(2, 0, WV, srcB + t3 * 64, lsu + 49152, )      // buf1.A h0 (t3)
  }

  // epilogue: D row=(lane>>4)*4+reg, col=lane&15 (m89-verified)
  EPIQ(0, 0, 0)
  EPIQ(1, 0, 1)
  EPIQ(2, 1, 0)
  EPIQ(3, 1, 1)
}

// ------- split-K kv: part[bid][e*128+d] = sum_{k in slab} pk[k,d]*v[k,e] ----
// also computes s-partials (column sums of pk over the slab) from registers.
__global__ __launch_bounds__(256, 2) void k_kv2(const u16* __restrict__ pk,
                                                const u16* __restrict__ v,
                                                float* __restrict__ part,
                                                float* __restrict__ spart) {
  int nh = blockIdx.x >> 3, slab = blockIdx.x & 7;
  int n = nh >> 4, h = nh & 15;
  __shared__ u16 lsA[128 * 32];   // pk^T tile: [d][k]
  __shared__ u16 lsB[128 * 32];   // v^T tile:  [e][k]
  __shared__ float redS[32][128];
  int tid = threadIdx.x, lane = tid & 63, wid = tid >> 6;
  int wr = wid >> 1, wc = wid & 1;
  int kk = tid >> 3;              // 0..31 (k within 32-k slab)
  int dg = (tid & 7) * 16;        // 0..112 (16 cols per thread)
  size_t rowbase = ((size_t)(n * 4096 + slab * 512) + kk) * 2048 + h * 128 + dg;
  int r = lane & 15, ko = (lane >> 4) * 8;
  fx4 acc[4][4] = {};
  float sA[16];
#pragma unroll
  for (int i = 0; i < 16; i++) sA[i] = 0.f;
  for (int k0 = 0; k0 < 512; k0 += 32) {
    __syncthreads();
    bh8 a0 = *(const bh8*)(pk + rowbase + (size_t)k0 * 2048);
    bh8 a1 = *(const bh8*)(pk + rowbase + (size_t)k0 * 2048 + 8);
    bh8 b0 = *(const bh8*)(v + rowbase + (size_t)k0 * 2048);
    bh8 b1 = *(const bh8*)(v + rowbase + (size_t)k0 * 2048 + 8);
#pragma unroll
    for (int i = 0; i < 8; i++) {
      sA[i] += bf2f((u16)a0[i]);
      sA[8 + i] += bf2f((u16)a1[i]);
    }
#pragma unroll
    for (int i = 0; i < 8; i++) {
      lsA[(dg + i) * 32 + kk] = (u16)a0[i];
      lsA[(dg + 8 + i) * 32 + kk] = (u16)a1[i];
      lsB[(dg + i) * 32 + kk] = (u16)b0[i];
      lsB[(dg + 8 + i) * 32 + kk] = (u16)b1[i];
    }
    __syncthreads();
    bh8 af[4], bfr[4];
#pragma unroll
    for (int mi = 0; mi < 4; mi++)
      af[mi] = *(const bh8*)&lsA[(wr * 64 + mi * 16 + r) * 32 + ko];
#pragma unroll
    for (int ni = 0; ni < 4; ni++)
      bfr[ni] = *(const bh8*)&lsB[(wc * 64 + ni * 16 + r) * 32 + ko];
#pragma unroll
    for (int mi = 0; mi < 4; mi++)
#pragma unroll
      for (int ni = 0; ni < 4; ni++)
        acc[mi][ni] = __builtin_amdgcn_mfma_f32_16x16x32_bf16(af[mi], bfr[ni],
                                                              acc[mi][ni], 0, 0, 0);
  }
  // D rows = d, cols = e; store f32 partial at [e][d]
#pragma unroll
  for (int mi = 0; mi < 4; mi++)
#pragma unroll
    for (int ni = 0; ni < 4; ni++)
#pragma unroll
      for (int j = 0; j < 4; j++) {
        int d = wr * 64 + mi * 16 + (lane >> 4) * 4 + j;
        int e = wc * 64 + ni * 16 + (lane & 15);
        part[(size_t)blockIdx.x * 16384 + e * 128 + d] = acc[mi][ni][j];
      }
  // s partial reduce over kk
#pragma unroll
  for (int i = 0; i < 16; i++) redS[kk][dg + i] = sA[i];
  __syncthreads();
  if (tid < 128) {
    float s = 0.f;
#pragma unroll
    for (int p = 0; p < 32; p++) s += redS[p][tid];
    spart[blockIdx.x * 128 + tid] = s;
  }
}

// ------- reduce split-K partials -> kvT (bf16) and s (f32) -------
__global__ __launch_bounds__(256) void k_red(const float* __restrict__ part,
                                             const float* __restrict__ spart,
                                             u16* __restrict__ kvT,
                                             float* __restrict__ sb) {
  int nh = blockIdx.x, tid = threadIdx.x;
  for (int i = tid; i < 16384; i += 256) {
    float s = 0.f;
#pragma unroll
    for (int sl = 0; sl < 8; sl++) s += part[(size_t)(nh * 8 + sl) * 16384 + i];
    kvT[(size_t)nh * 16384 + i] = f2bf(s);
  }
  if (tid < 128) {
    float s = 0.f;
#pragma unroll
    for (int sl = 0; sl < 8; sl++) s += spart[(nh * 8 + sl) * 128 + tid];
    sb[nh * 128 + tid] = s;
  }
}

// ---------------- final: out = (pq @ kv) / (pq @ s), query-masked ----------
__global__ __launch_bounds__(256, 2) void k_att(
    const u16* __restrict__ pq, const u16* __restrict__ kvT,
    const float* __restrict__ s, const int* __restrict__ qmask,
    float* __restrict__ out) {
  int b = blockIdx.x;
  int lt = b & 31, h = (b >> 5) & 15, nb = b >> 9;
  int l0 = lt * 128;
  __shared__ u16 lsQ[128 * 128];
  __shared__ u16 lsKV[128 * 128];
  __shared__ float lsS[128];
  __shared__ float lsDen[128];
  int tid = threadIdx.x, lane = tid & 63, wid = tid >> 6;

  int row = tid >> 1, part = tid & 1;
  const u16* gq = pq + ((size_t)(nb * 4096 + l0 + row)) * 2048 + h * 128 + part * 64;
  const u16* gk = kvT + ((size_t)(nb * 16 + h) * 128 + row) * 128 + part * 64;
  int sw = (row & 7) << 3;
#pragma unroll
  for (int j = 0; j < 8; j++) {
    bh8 vq = *(const bh8*)(gq + j * 8);
    bh8 vk = *(const bh8*)(gk + j * 8);
    int ci = (part * 64 + j * 8) ^ sw;
    *(bh8*)&lsQ[row * 128 + ci] = vq;
    *(bh8*)&lsKV[row * 128 + ci] = vk;
  }
  if (tid < 128) lsS[tid] = s[(nb * 16 + h) * 128 + tid];
  __syncthreads();

  if (tid < 128) {
    int rr = tid, swr = (rr & 7) << 3;
    float dsum = 0.f;
    for (int dd = 0; dd < 128; dd++) {
      int d = (dd + rr) & 127;
      dsum += bf2f(lsQ[rr * 128 + (d ^ swr)]) * lsS[d];
    }
    lsDen[rr] = dsum;
  }
  __syncthreads();

  int wr = wid >> 1, wc = wid & 1;
  int r = lane & 15, ko = (lane >> 4) * 8;
  fx4 acc[4][4] = {};
#pragma unroll
  for (int ks = 0; ks < 4; ks++) {
    bh8 af[4], bfr[4];
#pragma unroll
    for (int mi = 0; mi < 4; mi++) {
      int rw = wr * 64 + mi * 16 + r;
      af[mi] = *(const bh8*)&lsQ[rw * 128 + ((ks * 32 + ko) ^ ((rw & 7) << 3))];
    }
#pragma unroll
    for (int ni = 0; ni < 4; ni++) {
      int rw = wc * 64 + ni * 16 + r;
      bfr[ni] = *(const bh8*)&lsKV[rw * 128 + ((ks * 32 + ko) ^ ((rw & 7) << 3))];
    }
#pragma unroll
    for (int mi = 0; mi < 4; mi++)
#pragma unroll
      for (int ni = 0; ni < 4; ni++)
        acc[mi][ni] = __builtin_amdgcn_mfma_f32_16x16x32_bf16(af[mi], bfr[ni],
                                                              acc[mi][ni], 0, 0, 0);
  }
#pragma unroll
  for (int mi = 0; mi < 4; mi++)
#pragma unroll
    for (int ni = 0; ni < 4; ni++)
#pragma unroll
      for (int j = 0; j < 4; j++) {
        int li = wr * 64 + mi * 16 + (lane >> 4) * 4 + j;
        int e = wc * 64 + ni * 16 + (lane & 15);
        int l = l0 + li;
        float v = qmask[nb * 4096 + l] ? 0.f : acc[mi][ni][j] / lsDen[li];
        out[((size_t)(nb * 4096 + l)) * 2048 + h * 128 + e] = v;
      }
}

// ---------------- launch ----------------
extern "C" void kernel_launch(void* const* d_in, const int* in_sizes, int n_in,
                              void* d_out, int out_size, void* d_ws, size_t ws_size,
                              hipStream_t stream) {
  const float* query = (const float*)d_in[0];
  const float* key   = (const float*)d_in[1];
  const float* Wq    = (const float*)d_in[2];
  const float* Wk    = (const float*)d_in[3];
  const float* Wv    = (const float*)d_in[4];
  const int* qmask   = (const int*)d_in[5];
  const int* kmask   = (const int*)d_in[6];
  float* out = (float*)d_out;
  char* ws = (char*)d_ws;

  u16* qb   = (u16*)(ws + 0);
  u16* kb   = (u16*)(ws + 67108864ull);
  u16* Wqb  = (u16*)(ws + 134217728ull);
  u16* Wkb  = (u16*)(ws + 142606336ull);
  u16* Wvb  = (u16*)(ws + 150994944ull);
  u16* pq   = (u16*)(ws + 159383552ull);
  u16* kvT  = (u16*)(ws + 226492416ull);
  float* sb = (float*)(ws + 228589568ull);
  // split-K partials live in qb's region (dead after the first GEMM)
  float* kvpart = (float*)(ws + 0);            // 512 * 16384 * 4 = 33.5 MB
  float* spart  = (float*)(ws + 33554432ull);  // 512 * 128 * 4 = 256 KB
  // pk and v die before k_att -> live in d_out
  u16* pk = (u16*)d_out;
  u16* vb = (u16*)d_out + 33554432ull;

  k_cvt<<<2048, 256, 0, stream>>>(query, qb, 33554432 / 4);
  k_cvt<<<2048, 256, 0, stream>>>(key, kb, 33554432 / 4);
  k_cvt<<<512, 256, 0, stream>>>(Wq, Wqb, 4194304 / 4);
  k_cvt<<<512, 256, 0, stream>>>(Wk, Wkb, 4194304 / 4);
  k_cvt<<<512, 256, 0, stream>>>(Wv, Wvb, 4194304 / 4);

  k_gemm256<1><<<512, 512, 131072, stream>>>(qb, Wqb, pq, nullptr);
  k_gemm256<2><<<512, 512, 131072, stream>>>(kb, Wkb, pk, kmask);
  k_gemm256<0><<<512, 512, 131072, stream>>>(kb, Wvb, vb, nullptr);

  k_kv2<<<512, 256, 0, stream>>>(pk, vb, kvpart, spart);
  k_red<<<64, 256, 0, stream>>>(kvpart, spart, kvT, sb);
  k_att<<<2048, 256, 0, stream>>>(pq, kvT, sb, qmask, out);
}

// Round 8
// 739.116 us; speedup vs baseline: 3.0682x; 1.0079x over previous
//
#include <hip/hip_runtime.h>
#include <stdint.h>

typedef __attribute__((ext_vector_type(8))) short    bh8;   // 8 x bf16 (4 VGPR)
typedef __attribute__((ext_vector_type(4))) float    fx4;   // MFMA acc
typedef __attribute__((ext_vector_type(4))) float    f4v;
typedef unsigned short u16;
typedef __attribute__((ext_vector_type(4))) unsigned short u16x4;

#define DEV static __device__ __forceinline__

DEV u16 f2bf(float f) {                       // RNE fp32 -> bf16
  unsigned u = __float_as_uint(f);
  u += 0x7FFFu + ((u >> 16) & 1u);
  return (u16)(u >> 16);
}
DEV float bf2f(u16 s) { return __uint_as_float(((unsigned)s) << 16); }
DEV float softplus_f(float x) { return fmaxf(x, 0.f) + log1pf(expf(-fabsf(x))); }

DEV void gload_lds16(const u16* g, u16* l) {  // 16B/lane async global->LDS
  __builtin_amdgcn_global_load_lds(
      (const __attribute__((address_space(1))) unsigned int*)g,
      (__attribute__((address_space(3))) unsigned int*)l, 16, 0, 0);
}
DEV void stage2(const u16* s, u16* d) {       // one 128-row piece of a half-tile
  gload_lds16(s, d);
  gload_lds16(s + 131072, d + 4096);          // +64 rows (ld = 2048)
}

// ---------------- fp32 -> bf16 convert (vectorized) ----------------
__global__ __launch_bounds__(256) void k_cvt(const float* __restrict__ in,
                                             u16* __restrict__ out, int n4) {
  int i = blockIdx.x * 256 + threadIdx.x;
  int stride = gridDim.x * 256;
  for (; i < n4; i += stride) {
    f4v v = ((const f4v*)in)[i];
    u16x4 o;
    o.x = f2bf(v.x); o.y = f2bf(v.y); o.z = f2bf(v.z); o.w = f2bf(v.w);
    ((u16x4*)out)[i] = o;
  }
}

// ================= 256x256 8-phase GEMM (T2+T3+T4+T5) =================
// C[i,j] = sum_k A[i,k]*B[j,k]; M=16384, N=2048, K=2048 hardcoded.
// LDS (u16 idx): buf0.A h0=0 h1=8192 | buf0.B h0=16384 h1=24576
//                buf1.A h0=32768 h1=40960 | buf1.B h0=49152 h1=57344
// Tiles 256r x 64c row-major; ds_read XOR-swizzle idx ^= (row&7)<<3;
// staging = linear LDS dest + inverse-swizzled global source (rule #21).
// XCD-aware 2D chunked mapping: XCD=bid%8 owns A-panels [8x,8x+8) exclusively.
// EVEN read schedule (m201-style): phases grouped by K-slice, reads/phase
// {8,8,4,4} b128/wave (max 8) so LDS port overlaps MFMA instead of bursting.

#define MM(a, b, c) __builtin_amdgcn_mfma_f32_16x16x32_bf16(a, b, c, 0, 0, 0)
#define LD(BASE, RR, KS) \
  (*(const bh8*)&lsg[(BASE) + (RR) * 64 + ((((KS) * 32) + ko8) ^ swz)])

#define DECLQ(Q)                                                          \
  fx4 acc##Q##00 = {}, acc##Q##01 = {}, acc##Q##10 = {}, acc##Q##11 = {}, \
      acc##Q##20 = {}, acc##Q##21 = {}, acc##Q##30 = {}, acc##Q##31 = {}

#define WL asm volatile("s_waitcnt lgkmcnt(0)")
#define WV asm volatile("s_waitcnt vmcnt(4)"); asm volatile("s_waitcnt lgkmcnt(0)")

// 4 A-fragment reads of one K-slice KS from A-half at LDS base AB
#define LDA4(AB, KS)                                                     \
  a_0##KS = LD(AB, arow0,      KS); a_1##KS = LD(AB, arow0 + 16, KS);    \
  a_2##KS = LD(AB, arow0 + 32, KS); a_3##KS = LD(AB, arow0 + 48, KS);

// 2 B-fragment reads (ni=0,1) of K-slice KS from B-half BN at base BB
#define LDB2(BN, BB, KS)                                                 \
  b##BN##_0##KS = LD(BB, brow0,      KS);                                \
  b##BN##_1##KS = LD(BB, brow0 + 16, KS);

// 8 MFMA: quadrant Q (A-frags a_*KS x B-half BN frags) at K-slice KS
#define MFMA8(Q, BN, KS)                                                 \
  acc##Q##00 = MM(a_0##KS, b##BN##_0##KS, acc##Q##00);                   \
  acc##Q##01 = MM(a_0##KS, b##BN##_1##KS, acc##Q##01);                   \
  acc##Q##10 = MM(a_1##KS, b##BN##_0##KS, acc##Q##10);                   \
  acc##Q##11 = MM(a_1##KS, b##BN##_1##KS, acc##Q##11);                   \
  acc##Q##20 = MM(a_2##KS, b##BN##_0##KS, acc##Q##20);                   \
  acc##Q##21 = MM(a_2##KS, b##BN##_1##KS, acc##Q##21);                   \
  acc##Q##30 = MM(a_3##KS, b##BN##_0##KS, acc##Q##30);                   \
  acc##Q##31 = MM(a_3##KS, b##BN##_1##KS, acc##Q##31);

// LOADS go in __VA_ARGS__
#define PHASE(MFMAS, WAITS, SSRC, SDST, ...) {  \
  __VA_ARGS__                                   \
  stage2(SSRC, SDST);                           \
  __builtin_amdgcn_s_barrier();                 \
  __builtin_amdgcn_s_setprio(1);                \
  MFMAS                                         \
  __builtin_amdgcn_s_setprio(0);                \
  WAITS;                                        \
  __builtin_amdgcn_s_barrier();                 \
}

// store one 16x16 fragment (4 rows x-w), with epilogue EPI
#define STE(AC, EL, JOFF) {                                                   \
  float v = AC.EL;                                                            \
  if (EPI >= 1) v = softplus_f(v);                                            \
  if (EPI == 2) { if (mask[gi0 + JOFF]) v = 0.f; }                            \
  C[(size_t)(gi0 + JOFF) * 2048 + gj] = f2bf(v);                              \
}
#define ST1(AC, QR, QC, MI, NI) {                                             \
  int gi0 = bm0 + (QR) * 128 + wr * 64 + (MI) * 16 + (lane >> 4) * 4;         \
  int gj  = bn0 + (QC) * 128 + wc * 32 + (NI) * 16 + l15;                     \
  STE(AC, x, 0) STE(AC, y, 1) STE(AC, z, 2) STE(AC, w, 3)                     \
}
#define EPIQ(Q, QR, QC)                                                       \
  ST1(acc##Q##00, QR, QC, 0, 0) ST1(acc##Q##01, QR, QC, 0, 1)                 \
  ST1(acc##Q##10, QR, QC, 1, 0) ST1(acc##Q##11, QR, QC, 1, 1)                 \
  ST1(acc##Q##20, QR, QC, 2, 0) ST1(acc##Q##21, QR, QC, 2, 1)                 \
  ST1(acc##Q##30, QR, QC, 3, 0) ST1(acc##Q##31, QR, QC, 3, 1)

template <int EPI>   // 0 plain, 1 softplus, 2 softplus + row-mask zero
__global__ __launch_bounds__(512, 2) void k_gemm256(
    const u16* __restrict__ A, const u16* __restrict__ B, u16* __restrict__ C,
    const int* __restrict__ mask) {
  extern __shared__ u16 lsg[];                 // 128 KiB dynamic
  int tid = threadIdx.x, lane = tid & 63, wid = tid >> 6;
  // XCD-aware 2D chunk: XCD x = bid%8 owns m-tiles [8x, 8x+8), n = i>>3.
  int xcd = blockIdx.x & 7, i = blockIdx.x >> 3;
  int bm0 = (xcd * 8 + (i & 7)) << 8;          // 64 M-tiles, XCD-exclusive
  int bn0 = (i >> 3) << 8;                     // 8 N-tiles
  int wr = wid >> 2, wc = wid & 3;
  int l15 = lane & 15, ko8 = (lane >> 4) * 8;
  int swz = (l15 & 7) << 3;
  int arow0 = wr * 64 + l15, brow0 = wc * 32 + l15;
  int lr = lane >> 3, cg = (lane & 7) ^ lr;    // inverse-swizzled source granule
  const u16* srcA = A + (size_t)(bm0 + wid * 8 + lr) * 2048 + cg * 8;
  const u16* srcB = B + (size_t)(bn0 + wid * 8 + lr) * 2048 + cg * 8;
  u16* lsu = lsg + wid * 512;                  // wave-uniform stage dest base

  DECLQ(0); DECLQ(1); DECLQ(2); DECLQ(3);
  bh8 a_00 = {}, a_01 = {}, a_10 = {}, a_11 = {},
      a_20 = {}, a_21 = {}, a_30 = {}, a_31 = {};
  bh8 b0_00 = {}, b0_01 = {}, b0_10 = {}, b0_11 = {};
  bh8 b1_00 = {}, b1_01 = {}, b1_10 = {}, b1_11 = {};

  // prologue: tile0 all 4 halves + tile1 A-h0,B-h0; vmcnt(4) -> buf0 resident
  stage2(srcA, lsu + 0);                       // buf0.A h0  (t0)
  stage2(srcB, lsu + 16384);                   // buf0.B h0
  stage2(srcA + 262144, lsu + 8192);           // buf0.A h1
  stage2(srcB + 262144, lsu + 24576);          // buf0.B h1
  stage2(srcA + 64, lsu + 32768);              // buf1.A h0  (t1)
  stage2(srcB + 64, lsu + 49152);              // buf1.B h0
  asm volatile("s_waitcnt vmcnt(4)");
  __builtin_amdgcn_s_barrier();

  for (int it = 0; it < 16; it++) {
    int t1 = 2 * it + 1;
    int t2 = (2 * it + 2) & 31;                // wrapped prefetch (dup, unread)
    int t3 = (2 * it + 3) & 31;
    // ---- phases 1-4: tile 2it from buf0; reads {8,8,4,4} ----
    PHASE(MFMA8(0, 0, 0) MFMA8(1, 1, 0), WL,
          srcA + 262144 + t1 * 64, lsu + 40960,              // buf1.A h1 (t1)
          LDA4(0, 0) LDB2(0, 16384, 0) LDB2(1, 24576, 0))
    PHASE(MFMA8(0, 0, 1) MFMA8(1, 1, 1), WL,
          srcB + 262144 + t1 * 64, lsu + 57344,              // buf1.B h1 (t1)
          LDA4(0, 1) LDB2(0, 16384, 1) LDB2(1, 24576, 1))
    PHASE(MFMA8(2, 0, 0) MFMA8(3, 1, 0), WL,
          srcA + t2 * 64, lsu + 0,                           // buf0.A h0 (t2)
          LDA4(8192, 0))
    PHASE(MFMA8(2, 0, 1) MFMA8(3, 1, 1), WV,
          srcB + t2 * 64, lsu + 16384,                       // buf0.B h0 (t2)
          LDA4(8192, 1))
    // ---- phases 5-8: tile 2it+1 from buf1 ----
    PHASE(MFMA8(0, 0, 0) MFMA8(1, 1, 0), WL,
          srcA + 262144 + t2 * 64, lsu + 8192,               // buf0.A h1 (t2)
          LDA4(32768, 0) LDB2(0, 49152, 0) LDB2(1, 57344, 0))
    PHASE(MFMA8(0, 0, 1) MFMA8(1, 1, 1), WL,
          srcB + 262144 + t2 * 64, lsu + 24576,              // buf0.B h1 (t2)
          LDA4(32768, 1) LDB2(0, 49152, 1) LDB2(1, 57344, 1))
    PHASE(MFMA8(2, 0, 0) MFMA8(3, 1, 0), WL,
          srcA + t3 * 64, lsu + 32768,                       // buf1.A h0 (t3)
          LDA4(40960, 0))
    PHASE(MFMA8(2, 0, 1) MFMA8(3, 1, 1), WV,
          srcB + t3 * 64, lsu + 49152,                       // buf1.B h0 (t3)
          LDA4(40960, 1))
  }

  // epilogue: D row=(lane>>4)*4+reg, col=lane&15 (m89-verified)
  EPIQ(0, 0, 0)
  EPIQ(1, 0, 1)
  EPIQ(2, 1, 0)
  EPIQ(3, 1, 1)
}

// ------- split-K kv: part[bid][e*128+d] = sum_{k in slab} pk[k,d]*v[k,e] ----
// also computes s-partials (column sums of pk over the slab) from registers.
__global__ __launch_bounds__(256, 2) void k_kv2(const u16* __restrict__ pk,
                                                const u16* __restrict__ v,
                                                float* __restrict__ part,
                                                float* __restrict__ spart) {
  int nh = blockIdx.x >> 3, slab = blockIdx.x & 7;
  int n = nh >> 4, h = nh & 15;
  __shared__ u16 lsA[128 * 32];   // pk^T tile: [d][k]
  __shared__ u16 lsB[128 * 32];   // v^T tile:  [e][k]
  __shared__ float redS[32][128];
  int tid = threadIdx.x, lane = tid & 63, wid = tid >> 6;
  int wr = wid >> 1, wc = wid & 1;
  int kk = tid >> 3;              // 0..31 (k within 32-k slab)
  int dg = (tid & 7) * 16;        // 0..112 (16 cols per thread)
  size_t rowbase = ((size_t)(n * 4096 + slab * 512) + kk) * 2048 + h * 128 + dg;
  int r = lane & 15, ko = (lane >> 4) * 8;
  fx4 acc[4][4] = {};
  float sA[16];
#pragma unroll
  for (int i = 0; i < 16; i++) sA[i] = 0.f;
  for (int k0 = 0; k0 < 512; k0 += 32) {
    __syncthreads();
    bh8 a0 = *(const bh8*)(pk + rowbase + (size_t)k0 * 2048);
    bh8 a1 = *(const bh8*)(pk + rowbase + (size_t)k0 * 2048 + 8);
    bh8 b0 = *(const bh8*)(v + rowbase + (size_t)k0 * 2048);
    bh8 b1 = *(const bh8*)(v + rowbase + (size_t)k0 * 2048 + 8);
#pragma unroll
    for (int i = 0; i < 8; i++) {
      sA[i] += bf2f((u16)a0[i]);
      sA[8 + i] += bf2f((u16)a1[i]);
    }
#pragma unroll
    for (int i = 0; i < 8; i++) {
      lsA[(dg + i) * 32 + kk] = (u16)a0[i];
      lsA[(dg + 8 + i) * 32 + kk] = (u16)a1[i];
      lsB[(dg + i) * 32 + kk] = (u16)b0[i];
      lsB[(dg + 8 + i) * 32 + kk] = (u16)b1[i];
    }
    __syncthreads();
    bh8 af[4], bfr[4];
#pragma unroll
    for (int mi = 0; mi < 4; mi++)
      af[mi] = *(const bh8*)&lsA[(wr * 64 + mi * 16 + r) * 32 + ko];
#pragma unroll
    for (int ni = 0; ni < 4; ni++)
      bfr[ni] = *(const bh8*)&lsB[(wc * 64 + ni * 16 + r) * 32 + ko];
#pragma unroll
    for (int mi = 0; mi < 4; mi++)
#pragma unroll
      for (int ni = 0; ni < 4; ni++)
        acc[mi][ni] = __builtin_amdgcn_mfma_f32_16x16x32_bf16(af[mi], bfr[ni],
                                                              acc[mi][ni], 0, 0, 0);
  }
  // D rows = d, cols = e; store f32 partial at [e][d]
#pragma unroll
  for (int mi = 0; mi < 4; mi++)
#pragma unroll
    for (int ni = 0; ni < 4; ni++)
#pragma unroll
      for (int j = 0; j < 4; j++) {
        int d = wr * 64 + mi * 16 + (lane >> 4) * 4 + j;
        int e = wc * 64 + ni * 16 + (lane & 15);
        part[(size_t)blockIdx.x * 16384 + e * 128 + d] = acc[mi][ni][j];
      }
  // s partial reduce over kk
#pragma unroll
  for (int i = 0; i < 16; i++) redS[kk][dg + i] = sA[i];
  __syncthreads();
  if (tid < 128) {
    float s = 0.f;
#pragma unroll
    for (int p = 0; p < 32; p++) s += redS[p][tid];
    spart[blockIdx.x * 128 + tid] = s;
  }
}

// ------- reduce split-K partials -> kvT (bf16) and s (f32) -------
__global__ __launch_bounds__(256) void k_red(const float* __restrict__ part,
                                             const float* __restrict__ spart,
                                             u16* __restrict__ kvT,
                                             float* __restrict__ sb) {
  int nh = blockIdx.x, tid = threadIdx.x;
  for (int i = tid; i < 16384; i += 256) {
    float s = 0.f;
#pragma unroll
    for (int sl = 0; sl < 8; sl++) s += part[(size_t)(nh * 8 + sl) * 16384 + i];
    kvT[(size_t)nh * 16384 + i] = f2bf(s);
  }
  if (tid < 128) {
    float s = 0.f;
#pragma unroll
    for (int sl = 0; sl < 8; sl++) s += spart[(nh * 8 + sl) * 128 + tid];
    sb[nh * 128 + tid] = s;
  }
}

// ---------------- final: out = (pq @ kv) / (pq @ s), query-masked ----------
__global__ __launch_bounds__(256, 2) void k_att(
    const u16* __restrict__ pq, const u16* __restrict__ kvT,
    const float* __restrict__ s, const int* __restrict__ qmask,
    float* __restrict__ out) {
  int b = blockIdx.x;
  int lt = b & 31, h = (b >> 5) & 15, nb = b >> 9;
  int l0 = lt * 128;
  __shared__ u16 lsQ[128 * 128];
  __shared__ u16 lsKV[128 * 128];
  __shared__ float lsS[128];
  __shared__ float lsDen[128];
  int tid = threadIdx.x, lane = tid & 63, wid = tid >> 6;

  int row = tid >> 1, part = tid & 1;
  const u16* gq = pq + ((size_t)(nb * 4096 + l0 + row)) * 2048 + h * 128 + part * 64;
  const u16* gk = kvT + ((size_t)(nb * 16 + h) * 128 + row) * 128 + part * 64;
  int sw = (row & 7) << 3;
#pragma unroll
  for (int j = 0; j < 8; j++) {
    bh8 vq = *(const bh8*)(gq + j * 8);
    bh8 vk = *(const bh8*)(gk + j * 8);
    int ci = (part * 64 + j * 8) ^ sw;
    *(bh8*)&lsQ[row * 128 + ci] = vq;
    *(bh8*)&lsKV[row * 128 + ci] = vk;
  }
  if (tid < 128) lsS[tid] = s[(nb * 16 + h) * 128 + tid];
  __syncthreads();

  if (tid < 128) {
    int rr = tid, swr = (rr & 7) << 3;
    float dsum = 0.f;
    for (int dd = 0; dd < 128; dd++) {
      int d = (dd + rr) & 127;
      dsum += bf2f(lsQ[rr * 128 + (d ^ swr)]) * lsS[d];
    }
    lsDen[rr] = dsum;
  }
  __syncthreads();

  int wr = wid >> 1, wc = wid & 1;
  int r = lane & 15, ko = (lane >> 4) * 8;
  fx4 acc[4][4] = {};
#pragma unroll
  for (int ks = 0; ks < 4; ks++) {
    bh8 af[4], bfr[4];
#pragma unroll
    for (int mi = 0; mi < 4; mi++) {
      int rw = wr * 64 + mi * 16 + r;
      af[mi] = *(const bh8*)&lsQ[rw * 128 + ((ks * 32 + ko) ^ ((rw & 7) << 3))];
    }
#pragma unroll
    for (int ni = 0; ni < 4; ni++) {
      int rw = wc * 64 + ni * 16 + r;
      bfr[ni] = *(const bh8*)&lsKV[rw * 128 + ((ks * 32 + ko) ^ ((rw & 7) << 3))];
    }
#pragma unroll
    for (int mi = 0; mi < 4; mi++)
#pragma unroll
      for (int ni = 0; ni < 4; ni++)
        acc[mi][ni] = __builtin_amdgcn_mfma_f32_16x16x32_bf16(af[mi], bfr[ni],
                                                              acc[mi][ni], 0, 0, 0);
  }
#pragma unroll
  for (int mi = 0; mi < 4; mi++)
#pragma unroll
    for (int ni = 0; ni < 4; ni++)
#pragma unroll
      for (int j = 0; j < 4; j++) {
        int li = wr * 64 + mi * 16 + (lane >> 4) * 4 + j;
        int e = wc * 64 + ni * 16 + (lane & 15);
        int l = l0 + li;
        float v = qmask[nb * 4096 + l] ? 0.f : acc[mi][ni][j] / lsDen[li];
        out[((size_t)(nb * 4096 + l)) * 2048 + h * 128 + e] = v;
      }
}

// ---------------- launch ----------------
extern "C" void kernel_launch(void* const* d_in, const int* in_sizes, int n_in,
                              void* d_out, int out_size, void* d_ws, size_t ws_size,
                              hipStream_t stream) {
  const float* query = (const float*)d_in[0];
  const float* key   = (const float*)d_in[1];
  const float* Wq    = (const float*)d_in[2];
  const float* Wk    = (const float*)d_in[3];
  const float* Wv    = (const float*)d_in[4];
  const int* qmask   = (const int*)d_in[5];
  const int* kmask   = (const int*)d_in[6];
  float* out = (float*)d_out;
  char* ws = (char*)d_ws;

  u16* qb   = (u16*)(ws + 0);
  u16* kb   = (u16*)(ws + 67108864ull);
  u16* Wqb  = (u16*)(ws + 134217728ull);
  u16* Wkb  = (u16*)(ws + 142606336ull);
  u16* Wvb  = (u16*)(ws + 150994944ull);
  u16* pq   = (u16*)(ws + 159383552ull);
  u16* kvT  = (u16*)(ws + 226492416ull);
  float* sb = (float*)(ws + 228589568ull);
  // split-K partials live in qb's region (dead after the first GEMM)
  float* kvpart = (float*)(ws + 0);            // 512 * 16384 * 4 = 33.5 MB
  float* spart  = (float*)(ws + 33554432ull);  // 512 * 128 * 4 = 256 KB
  // pk and v die before k_att -> live in d_out
  u16* pk = (u16*)d_out;
  u16* vb = (u16*)d_out + 33554432ull;

  k_cvt<<<2048, 256, 0, stream>>>(query, qb, 33554432 / 4);
  k_cvt<<<2048, 256, 0, stream>>>(key, kb, 33554432 / 4);
  k_cvt<<<512, 256, 0, stream>>>(Wq, Wqb, 4194304 / 4);
  k_cvt<<<512, 256, 0, stream>>>(Wk, Wkb, 4194304 / 4);
  k_cvt<<<512, 256, 0, stream>>>(Wv, Wvb, 4194304 / 4);

  k_gemm256<1><<<512, 512, 131072, stream>>>(qb, Wqb, pq, nullptr);
  k_gemm256<2><<<512, 512, 131072, stream>>>(kb, Wkb, pk, kmask);
  k_gemm256<0><<<512, 512, 131072, stream>>>(kb, Wvb, vb, nullptr);

  k_kv2<<<512, 256, 0, stream>>>(pk, vb, kvpart, spart);
  k_red<<<64, 256, 0, stream>>>(kvpart, spart, kvT, sb);
  k_att<<<2048, 256, 0, stream>>>(pq, kvT, sb, qmask, out);
}